// Round 10
// baseline (380.196 us; speedup 1.0000x reference)
//
#include <hip/hip_runtime.h>

// ===== types =====
typedef __attribute__((ext_vector_type(8))) short short8;       // 8 x bf16 bits
typedef __attribute__((ext_vector_type(8))) unsigned short ushort8;
typedef __attribute__((ext_vector_type(4))) float f32x4;
typedef __attribute__((ext_vector_type(16))) float f32x16;
typedef __attribute__((ext_vector_type(2))) unsigned int uint2v;
typedef unsigned int uint32;

__device__ __forceinline__ unsigned short f2bf(float f){
  union { float f; unsigned int u; } x; x.f = f;
  unsigned int u = x.u;
  u += 0x7fffu + ((u >> 16) & 1u);   // RNE
  return (unsigned short)(u >> 16);
}
__device__ __forceinline__ float bf2f(unsigned short s){
  union { float f; unsigned int u; } x; x.u = ((uint32)s) << 16; return x.f;
}

typedef __attribute__((address_space(1))) void gvoid;
typedef __attribute__((address_space(3))) void lvoid;
__device__ __forceinline__ void gload_lds16(const void* g, void* l){
  __builtin_amdgcn_global_load_lds((gvoid*)g, (lvoid*)l, 16, 0, 0);
}

__device__ __forceinline__ f32x16 mfma32(short8 a, short8 b, f32x16 c){
  return __builtin_amdgcn_mfma_f32_32x32x16_bf16(a, b, c, 0, 0, 0);
}

__device__ __forceinline__ uint32 cvtpk_bf(float lo, float hi){
  uint32 r;
  asm("v_cvt_pk_bf16_f32 %0, %1, %2" : "=v"(r) : "v"(lo), "v"(hi));
  return r;
}
__device__ __forceinline__ void plswap(uint32& a, uint32& b){
  auto r = __builtin_amdgcn_permlane32_swap(a, b, false, false);
  a = r[0]; b = r[1];
}

#if __has_builtin(__builtin_amdgcn_exp2f)
__device__ __forceinline__ float exp2g(float x){ return __builtin_amdgcn_exp2f(x); }
#else
__device__ __forceinline__ float exp2g(float x){ return exp2f(x); }
#endif
#if __has_builtin(__builtin_amdgcn_rcpf)
__device__ __forceinline__ float rcpg(float x){ return __builtin_amdgcn_rcpf(x); }
#else
__device__ __forceinline__ float rcpg(float x){ return 1.0f / x; }
#endif

// fast gelu: v - v/(1+exp2(2*log2e * u)), u = c0*(v + 0.044715 v^3)
__device__ __forceinline__ float gelu_fast(float v){
  const float u = 0.7978845608028654f * (v + 0.044715f * v * v * v);
  const float E = exp2g(2.8853900817779268f * u);
  return v - v * rcpg(1.0f + E);
}

__device__ __forceinline__ f32x16 zero16(){
  f32x16 z;
  #pragma unroll
  for (int i = 0; i < 16; i++) z[i] = 0.0f;
  return z;
}

// ===== weight transpose + fp32->bf16: w[K][N] -> wt[N][K] =====
__global__ __launch_bounds__(256) void wtrans_kernel(
    const float* __restrict__ w, unsigned short* __restrict__ wt, int K, int N)
{
  __shared__ float tile[32][33];
  const int n0 = blockIdx.x * 32;
  const int k0 = blockIdx.y * 32;
  const int t = threadIdx.x;
  #pragma unroll
  for (int i = 0; i < 4; i++){
    const int e = t + i * 256;
    const int r = e >> 5, c = e & 31;
    tile[r][c] = w[(size_t)(k0 + r) * N + n0 + c];
  }
  __syncthreads();
  #pragma unroll
  for (int i = 0; i < 4; i++){
    const int e = t + i * 256;
    const int r = e >> 5, c = e & 31;   // r = n-local, c = k-local
    wt[(size_t)(n0 + r) * K + k0 + c] = f2bf(tile[c][r]);
  }
}

// ===== V transpose: qkv[8192][3072] (v at col 2048+h*64) -> vt[bh][64][2048] bf16 =====
__global__ __launch_bounds__(256) void vtrans_kernel(
    const unsigned short* __restrict__ qkv, unsigned short* __restrict__ vt)
{
  __shared__ unsigned short tile[32][33];
  const int bh = blockIdx.z;
  const int b = bh >> 4, h = bh & 15;
  const int t0 = blockIdx.x * 32;
  const int f0 = blockIdx.y * 32;
  const int t = threadIdx.x;
  #pragma unroll
  for (int i = 0; i < 4; i++){
    const int e = t + i * 256;
    const int r = e >> 5, c = e & 31;   // r = t-local, c = feat-local
    tile[r][c] = qkv[(size_t)(b * 2048 + t0 + r) * 3072 + 2048 + h * 64 + f0 + c];
  }
  __syncthreads();
  #pragma unroll
  for (int i = 0; i < 4; i++){
    const int e = t + i * 256;
    const int r = e >> 5, c = e & 31;   // r = feat-local, c = t-local
    vt[((size_t)bh * 64 + f0 + r) * 2048 + t0 + c] = tile[c][r];
  }
}

// ===== LayerNorm fp32 -> bf16 (row = 1024) =====
__global__ __launch_bounds__(256) void ln_kernel(
    const float* __restrict__ x, const float* __restrict__ w, const float* __restrict__ b,
    unsigned short* __restrict__ out)
{
  const int row = blockIdx.x;
  const int t = threadIdx.x;
  const float4 v = ((const float4*)(x + (size_t)row * 1024))[t];
  float s  = v.x + v.y + v.z + v.w;
  float s2 = v.x * v.x + v.y * v.y + v.z * v.z + v.w * v.w;
  #pragma unroll
  for (int off = 32; off > 0; off >>= 1){
    s  += __shfl_xor(s, off);
    s2 += __shfl_xor(s2, off);
  }
  __shared__ float ps[8];
  const int wid = t >> 6;
  if ((t & 63) == 0){ ps[wid] = s; ps[4 + wid] = s2; }
  __syncthreads();
  s  = ps[0] + ps[1] + ps[2] + ps[3];
  s2 = ps[4] + ps[5] + ps[6] + ps[7];
  const float mu  = s * (1.0f / 1024.0f);
  const float var = s2 * (1.0f / 1024.0f) - mu * mu;
  const float rs  = rsqrtf(var + 1e-5f);
  const float4 wv = ((const float4*)w)[t];
  const float4 bv = ((const float4*)b)[t];
  ushort4 ov;
  ov.x = f2bf((v.x - mu) * rs * wv.x + bv.x);
  ov.y = f2bf((v.y - mu) * rs * wv.y + bv.y);
  ov.z = f2bf((v.z - mu) * rs * wv.z + bv.z);
  ov.w = f2bf((v.w - mu) * rs * wv.w + bv.w);
  ((ushort4*)(out + (size_t)row * 1024))[t] = ov;
}

#define EPI_BF16   0
#define EPI_RESF32 1
#define EPI_GELU   2

// ===== GEMM gemm5 (mfma32): BM=128 BN=256, 2 blocks/CU (N>=2048 shapes) ====
// 4 waves (1M x 4N), per-wave 128x64 = 4 m-blocks x 2 n-blocks of 32x32.
// mfma_f32_32x32x16_bf16 (2382-2495 TF ubench vs 2075 for 16x16x32; halves
// MFMA instruction count at identical LDS traffic: still 12 ds_read_b128 per
// slice for 16 mfma32). C layout: col=lane&31, row=(r&3)+8*(r>>2)+4*hi
// (verified in attn kernel). BK=32 ring-3 (72KB -> 2 blocks/CU), counted
// vmcnt(6), one barrier/slice, compiler-interleaved body, 2-way swizzle
// both-sides (slot domain kh*2+hi ^ (row>>1)&3 - uniform per row-pair).
template<int EPI>
__global__ __launch_bounds__(256, 2) void gemm5_kernel(
    const unsigned short* __restrict__ A,
    const unsigned short* __restrict__ BT,
    const float* __restrict__ bias,
    const float* __restrict__ res,
    void* __restrict__ outp,
    int M, int N, int K)
{
  constexpr int SLOT = 24576;   // A 8KB + B 16KB
  __shared__ __align__(16) char lds[3 * SLOT];

  const int nwg = gridDim.x;
  const int bid = blockIdx.x;
  const int wg = (bid & 7) * (nwg >> 3) + (bid >> 3);
  const int NT = N >> 8;
  const int mt = wg / NT;
  const int nti = wg - mt * NT;
  const int m0 = mt << 7;
  const int n0 = nti << 8;

  const int tid = threadIdx.x;
  const int lane = tid & 63;
  const int wid = tid >> 6;          // wave = 64-col band
  const int l31 = lane & 31;
  const int hi = lane >> 5;

  const unsigned short* aSrc[2]; int aDst[2];
  #pragma unroll
  for (int l = 0; l < 2; l++){
    const int s = l * 256 + tid;
    const int r = s >> 2, c = s & 3;
    aSrc[l] = A + (size_t)(m0 + r) * K + ((c ^ ((r >> 1) & 3)) << 3);
    aDst[l] = s * 16;
  }
  const unsigned short* bSrc[4]; int bDst[4];
  #pragma unroll
  for (int l = 0; l < 4; l++){
    const int s = l * 256 + tid;
    const int r = s >> 2, c = s & 3;
    bSrc[l] = BT + (size_t)(n0 + r) * K + ((c ^ ((r >> 1) & 3)) << 3);
    bDst[l] = 8192 + s * 16;
  }

  // fragment read offsets: A[row=mb*32+l31][k-chunk kh*2+hi], swizzled slot
  int aOff[4][2], bOff[2][2];
  #pragma unroll
  for (int mb = 0; mb < 4; mb++){
    const int row = mb * 32 + l31;
    #pragma unroll
    for (int kh = 0; kh < 2; kh++)
      aOff[mb][kh] = row * 64 + (((kh * 2 + hi) ^ ((row >> 1) & 3)) << 4);
  }
  #pragma unroll
  for (int nb = 0; nb < 2; nb++){
    const int row = wid * 64 + nb * 32 + l31;
    #pragma unroll
    for (int kh = 0; kh < 2; kh++)
      bOff[nb][kh] = 8192 + row * 64 + (((kh * 2 + hi) ^ ((row >> 1) & 3)) << 4);
  }

  f32x16 acc[4][2];
  #pragma unroll
  for (int i = 0; i < 4; i++)
    #pragma unroll
    for (int j = 0; j < 2; j++) acc[i][j] = zero16();

#define STAGE5(sl, slot) do { \
    gload_lds16(aSrc[0] + (size_t)(sl) * 32, lds + (slot) + aDst[0]); \
    gload_lds16(aSrc[1] + (size_t)(sl) * 32, lds + (slot) + aDst[1]); \
    gload_lds16(bSrc[0] + (size_t)(sl) * 32, lds + (slot) + bDst[0]); \
    gload_lds16(bSrc[1] + (size_t)(sl) * 32, lds + (slot) + bDst[1]); \
    gload_lds16(bSrc[2] + (size_t)(sl) * 32, lds + (slot) + bDst[2]); \
    gload_lds16(bSrc[3] + (size_t)(sl) * 32, lds + (slot) + bDst[3]); \
  } while (0)

  const int NS = K >> 5;

  STAGE5(0, 0);
  STAGE5(1, SLOT);
  asm volatile("s_waitcnt vmcnt(6)" ::: "memory");
  __builtin_amdgcn_s_barrier();
  asm volatile("" ::: "memory");

  int cs = 0, cg = 2 * SLOT;
  for (int s = 0; s < NS; s++){
    short8 aF[4][2], bF[2][2];
    #pragma unroll
    for (int mb = 0; mb < 4; mb++)
      #pragma unroll
      for (int kh = 0; kh < 2; kh++)
        aF[mb][kh] = *(const short8*)(lds + cs + aOff[mb][kh]);
    #pragma unroll
    for (int nb = 0; nb < 2; nb++)
      #pragma unroll
      for (int kh = 0; kh < 2; kh++)
        bF[nb][kh] = *(const short8*)(lds + cs + bOff[nb][kh]);
    if (s + 2 < NS) STAGE5(s + 2, cg);
    #pragma unroll
    for (int mb = 0; mb < 4; mb++)
      #pragma unroll
      for (int nb = 0; nb < 2; nb++){
        acc[mb][nb] = mfma32(aF[mb][0], bF[nb][0], acc[mb][nb]);
        acc[mb][nb] = mfma32(aF[mb][1], bF[nb][1], acc[mb][nb]);
      }

    if (s + 2 < NS){
      asm volatile("s_waitcnt vmcnt(6)" ::: "memory");
    } else if (s + 1 < NS){
      asm volatile("s_waitcnt vmcnt(0)" ::: "memory");
    }
    __builtin_amdgcn_s_barrier();
    asm volatile("" ::: "memory");

    cs += SLOT; if (cs == 3 * SLOT) cs = 0;
    cg += SLOT; if (cg == 3 * SLOT) cg = 0;
  }
#undef STAGE5

  // epilogue: C row = m0 + mb*32 + (r&3)+8*(r>>2)+4*hi, col = n-band + l31
  #pragma unroll
  for (int mb = 0; mb < 4; mb++){
    #pragma unroll
    for (int nb = 0; nb < 2; nb++){
      const int ncol = n0 + wid * 64 + nb * 32 + l31;
      const float bv = bias[ncol];
      #pragma unroll
      for (int r = 0; r < 16; r++){
        const int mrow = m0 + mb * 32 + (r & 3) + 8 * (r >> 2) + 4 * hi;
        const size_t idx = (size_t)mrow * N + ncol;
        float v = acc[mb][nb][r] + bv;
        if (EPI == EPI_RESF32){
          ((float*)outp)[idx] = v + res[idx];
        } else if (EPI == EPI_GELU){
          ((unsigned short*)outp)[idx] = f2bf(gelu_fast(v));
        } else {
          ((unsigned short*)outp)[idx] = f2bf(v);
        }
      }
    }
  }
}

// ===== GEMM gemm7 (mfma32): N=1024 shapes (proj, fc2) =====================
// BM=128, BN=128, 256 thr = 4 waves (2M x 2N), per-wave 64x64 = 2x2 blocks
// of 32x32. 8 ds_read + 4 stage loads per slice for 8 mfma32 (was 16
// mfma16: matrix-pipe time -17%). Ring-3 48KB -> 3 blocks/CU, 3 waves/SIMD.
// Counted vmcnt(4), one barrier/slice, 2-way swizzle both-sides.
template<int EPI>
__global__ __launch_bounds__(256, 3) void gemm7_kernel(
    const unsigned short* __restrict__ A,
    const unsigned short* __restrict__ BT,
    const float* __restrict__ bias,
    const float* __restrict__ res,
    void* __restrict__ outp,
    int M, int N, int K)
{
  constexpr int SLOT = 16384;   // A 8KB + B 8KB
  __shared__ __align__(16) char lds[3 * SLOT];

  const int nwg = gridDim.x;
  const int bid = blockIdx.x;
  const int wg = (bid & 7) * (nwg >> 3) + (bid >> 3);
  const int NT = N >> 7;
  const int mt = wg / NT;
  const int nti = wg - mt * NT;
  const int m0 = mt << 7;
  const int n0 = nti << 7;

  const int tid = threadIdx.x;
  const int lane = tid & 63;
  const int wid = tid >> 6;
  const int wv_m = wid >> 1;     // 0..1 -> 64-row band
  const int wv_n = wid & 1;      // 0..1 -> 64-col band
  const int l31 = lane & 31;
  const int hi = lane >> 5;

  const unsigned short* aSrc[2]; int aDst[2];
  const unsigned short* bSrc[2]; int bDst[2];
  #pragma unroll
  for (int l = 0; l < 2; l++){
    const int s = l * 256 + tid;
    const int r = s >> 2, c = s & 3;
    const int co = (c ^ ((r >> 1) & 3)) << 3;
    aSrc[l] = A  + (size_t)(m0 + r) * K + co;
    bSrc[l] = BT + (size_t)(n0 + r) * K + co;
    aDst[l] = s * 16;
    bDst[l] = 8192 + s * 16;
  }

  int aOff[2][2], bOff[2][2];
  #pragma unroll
  for (int mb = 0; mb < 2; mb++){
    const int row = wv_m * 64 + mb * 32 + l31;
    #pragma unroll
    for (int kh = 0; kh < 2; kh++)
      aOff[mb][kh] = row * 64 + (((kh * 2 + hi) ^ ((row >> 1) & 3)) << 4);
  }
  #pragma unroll
  for (int nb = 0; nb < 2; nb++){
    const int row = wv_n * 64 + nb * 32 + l31;
    #pragma unroll
    for (int kh = 0; kh < 2; kh++)
      bOff[nb][kh] = 8192 + row * 64 + (((kh * 2 + hi) ^ ((row >> 1) & 3)) << 4);
  }

  f32x16 acc[2][2];
  #pragma unroll
  for (int i = 0; i < 2; i++)
    #pragma unroll
    for (int j = 0; j < 2; j++) acc[i][j] = zero16();

#define STAGE7(sl, slot) do { \
    gload_lds16(aSrc[0] + (size_t)(sl) * 32, lds + (slot) + aDst[0]); \
    gload_lds16(aSrc[1] + (size_t)(sl) * 32, lds + (slot) + aDst[1]); \
    gload_lds16(bSrc[0] + (size_t)(sl) * 32, lds + (slot) + bDst[0]); \
    gload_lds16(bSrc[1] + (size_t)(sl) * 32, lds + (slot) + bDst[1]); \
  } while (0)

  const int NS = K >> 5;

  STAGE7(0, 0);
  STAGE7(1, SLOT);
  asm volatile("s_waitcnt vmcnt(4)" ::: "memory");
  __builtin_amdgcn_s_barrier();
  asm volatile("" ::: "memory");

  int cs = 0, cg = 2 * SLOT;
  for (int s = 0; s < NS; s++){
    short8 aF[2][2], bF[2][2];
    #pragma unroll
    for (int mb = 0; mb < 2; mb++)
      #pragma unroll
      for (int kh = 0; kh < 2; kh++)
        aF[mb][kh] = *(const short8*)(lds + cs + aOff[mb][kh]);
    #pragma unroll
    for (int nb = 0; nb < 2; nb++)
      #pragma unroll
      for (int kh = 0; kh < 2; kh++)
        bF[nb][kh] = *(const short8*)(lds + cs + bOff[nb][kh]);
    if (s + 2 < NS) STAGE7(s + 2, cg);
    #pragma unroll
    for (int mb = 0; mb < 2; mb++)
      #pragma unroll
      for (int nb = 0; nb < 2; nb++){
        acc[mb][nb] = mfma32(aF[mb][0], bF[nb][0], acc[mb][nb]);
        acc[mb][nb] = mfma32(aF[mb][1], bF[nb][1], acc[mb][nb]);
      }

    if (s + 2 < NS){
      asm volatile("s_waitcnt vmcnt(4)" ::: "memory");
    } else if (s + 1 < NS){
      asm volatile("s_waitcnt vmcnt(0)" ::: "memory");
    }
    __builtin_amdgcn_s_barrier();
    asm volatile("" ::: "memory");

    cs += SLOT; if (cs == 3 * SLOT) cs = 0;
    cg += SLOT; if (cg == 3 * SLOT) cg = 0;
  }
#undef STAGE7

  #pragma unroll
  for (int mb = 0; mb < 2; mb++){
    #pragma unroll
    for (int nb = 0; nb < 2; nb++){
      const int ncol = n0 + wv_n * 64 + nb * 32 + l31;
      const float bv = bias[ncol];
      #pragma unroll
      for (int r = 0; r < 16; r++){
        const int mrow = m0 + wv_m * 64 + mb * 32 + (r & 3) + 8 * (r >> 2) + 4 * hi;
        const size_t idx = (size_t)mrow * N + ncol;
        float v = acc[mb][nb][r] + bv;
        if (EPI == EPI_RESF32){
          ((float*)outp)[idx] = v + res[idx];
        } else if (EPI == EPI_GELU){
          ((unsigned short*)outp)[idx] = f2bf(gelu_fast(v));
        } else {
          ((unsigned short*)outp)[idx] = f2bf(v);
        }
      }
    }
  }
}

// ===== causal flash attention (unchanged) =====
template<bool MASK>
__device__ __forceinline__ void attn_tile(
    const unsigned short* __restrict__ Kc, const unsigned short* __restrict__ Vc,
    const short8 (&qf)[4], int kvbase, int qg, int l31, int hi,
    float& m_r, float& lsum, f32x16& Oa, f32x16& Ob)
{
  f32x16 Sa = zero16();
  f32x16 Sb = zero16();
  const int xb = l31 & 7;
  #pragma unroll
  for (int kk = 0; kk < 4; kk++){
    const int x = kk * 2 + hi;
    const short8 k0 = *(const short8*)((const char*)Kc + l31 * 128 + ((x ^ xb) << 4));
    const short8 k1 = *(const short8*)((const char*)Kc + (l31 + 32) * 128 + ((x ^ xb) << 4));
    Sa = mfma32(k0, qf[kk], Sa);
    Sb = mfma32(k1, qf[kk], Sb);
  }
  if (MASK){
    #pragma unroll
    for (int r = 0; r < 16; r++){
      const int kva = kvbase + (r & 3) + 8 * (r >> 2) + 4 * hi;
      Sa[r] = (kva > qg)      ? -1e30f : Sa[r];
      Sb[r] = (kva + 32 > qg) ? -1e30f : Sb[r];
    }
  }
  float tmax = Sa[0];
  #pragma unroll
  for (int r = 1; r < 16; r++) tmax = fmaxf(tmax, Sa[r]);
  #pragma unroll
  for (int r = 0; r < 16; r++) tmax = fmaxf(tmax, Sb[r]);
  tmax = fmaxf(tmax, __shfl_xor(tmax, 32));
  if (__any(tmax > m_r + 10.0f)){
    const float mn = fmaxf(m_r, tmax);
    const float sc = exp2g(m_r - mn);
    m_r = mn;
    lsum *= sc;
    #pragma unroll
    for (int r = 0; r < 16; r++){ Oa[r] *= sc; Ob[r] *= sc; }
  }
  float rs = 0.0f;
  #pragma unroll
  for (int r = 0; r < 16; r++){
    Sa[r] = exp2g(Sa[r] - m_r); rs += Sa[r];
    Sb[r] = exp2g(Sb[r] - m_r); rs += Sb[r];
  }
  rs += __shfl_xor(rs, 32);
  lsum += rs;

  short8 pf[4];
  {
    uint32 a0 = cvtpk_bf(Sa[0], Sa[1]),   b0 = cvtpk_bf(Sa[4], Sa[5]);
    uint32 a1 = cvtpk_bf(Sa[2], Sa[3]),   b1 = cvtpk_bf(Sa[6], Sa[7]);
    plswap(a0, b0); plswap(a1, b1);
    uint32 a2 = cvtpk_bf(Sa[8], Sa[9]),   b2 = cvtpk_bf(Sa[12], Sa[13]);
    uint32 a3 = cvtpk_bf(Sa[10], Sa[11]), b3 = cvtpk_bf(Sa[14], Sa[15]);
    plswap(a2, b2); plswap(a3, b3);
    union { uint32 u[4]; short8 s; } m0, m1;
    m0.u[0] = a0; m0.u[1] = a1; m0.u[2] = b0; m0.u[3] = b1;
    m1.u[0] = a2; m1.u[1] = a3; m1.u[2] = b2; m1.u[3] = b3;
    pf[0] = m0.s; pf[1] = m1.s;
  }
  {
    uint32 a0 = cvtpk_bf(Sb[0], Sb[1]),   b0 = cvtpk_bf(Sb[4], Sb[5]);
    uint32 a1 = cvtpk_bf(Sb[2], Sb[3]),   b1 = cvtpk_bf(Sb[6], Sb[7]);
    plswap(a0, b0); plswap(a1, b1);
    uint32 a2 = cvtpk_bf(Sb[8], Sb[9]),   b2 = cvtpk_bf(Sb[12], Sb[13]);
    uint32 a3 = cvtpk_bf(Sb[10], Sb[11]), b3 = cvtpk_bf(Sb[14], Sb[15]);
    plswap(a2, b2); plswap(a3, b3);
    union { uint32 u[4]; short8 s; } m0, m1;
    m0.u[0] = a0; m0.u[1] = a1; m0.u[2] = b0; m0.u[3] = b1;
    m1.u[0] = a2; m1.u[1] = a3; m1.u[2] = b2; m1.u[3] = b3;
    pf[2] = m0.s; pf[3] = m1.s;
  }
  #pragma unroll
  for (int kk = 0; kk < 4; kk++){
    const int x = kk * 2 + hi;
    const short8 v0 = *(const short8*)((const char*)Vc + l31 * 128 + ((x ^ xb) << 4));
    const short8 v1 = *(const short8*)((const char*)Vc + (l31 + 32) * 128 + ((x ^ xb) << 4));
    Oa = mfma32(v0, pf[kk], Oa);
    Ob = mfma32(v1, pf[kk], Ob);
  }
}

__global__ __launch_bounds__(256) void attn_kernel(
    const unsigned short* __restrict__ qkv,
    const unsigned short* __restrict__ vt,
    unsigned short* __restrict__ y)
{
  __shared__ __align__(16) unsigned short Klds[2][4096];
  __shared__ __align__(16) unsigned short Vlds[2][4096];
  const int bid = blockIdx.x;
  const int bh = bid & 63;
  const int qb_i = bid >> 6;
  const int b = bh >> 4, h = bh & 15;
  const int qb0 = qb_i * 128;
  const int tid = threadIdx.x;
  const int w = tid >> 6;
  const int lane = tid & 63;
  const int l31 = lane & 31;
  const int hi = lane >> 5;

  const int qrow_g = b * 2048 + qb0 + w * 32 + l31;
  const unsigned short* qp = qkv + (size_t)qrow_g * 3072 + h * 64;
  short8 qf[4];
  #pragma unroll
  for (int kk = 0; kk < 4; kk++){
    short8 raw = *(const short8*)&qp[kk * 16 + hi * 8];
    #pragma unroll
    for (int j = 0; j < 8; j++)
      qf[kk][j] = (short)f2bf(bf2f((unsigned short)raw[j]) * 0.18033688011112042f);
  }

  const int sr = tid >> 3;
  const int ce = ((tid & 7) ^ (sr & 7)) * 8;
  const unsigned short* kb = qkv + (size_t)(b * 2048) * 3072 + 1024 + h * 64;
  const unsigned short* vb = vt + (size_t)bh * 64 * 2048;

  f32x16 Oa = zero16(), Ob = zero16();
  float m_r = -1e30f, lsum = 0.0f;
  const int qmin = qb0 + w * 32;
  const int qmax = qmin + 31;
  const int qg = qmin + l31;
  const int nkv = (qb0 >> 6) + 2;

#define STAGE(t, bb) do { \
    const size_t kro = (size_t)((t) * 64 + sr) * 3072; \
    gload_lds16(kb + kro + ce,                         (char*)&Klds[bb][0] + tid * 16); \
    gload_lds16(kb + kro + (size_t)32 * 3072 + ce,     (char*)&Klds[bb][0] + 4096 + tid * 16); \
    gload_lds16(vb + (size_t)sr * 2048 + (t) * 64 + ce,        (char*)&Vlds[bb][0] + tid * 16); \
    gload_lds16(vb + (size_t)(sr + 32) * 2048 + (t) * 64 + ce, (char*)&Vlds[bb][0] + 4096 + tid * 16); \
  } while (0)

  STAGE(0, 0);
  __syncthreads();
  int cur = 0;
  for (int kvt = 0; kvt < nkv; kvt++){
    if (kvt + 1 < nkv){
      if (cur) STAGE(kvt + 1, 0); else STAGE(kvt + 1, 1);
    }
    if (kvt * 64 <= qmax){
      if (kvt * 64 + 63 <= qmin)
        attn_tile<false>(Klds[cur], Vlds[cur], qf, kvt * 64, qg, l31, hi, m_r, lsum, Oa, Ob);
      else
        attn_tile<true >(Klds[cur], Vlds[cur], qf, kvt * 64, qg, l31, hi, m_r, lsum, Oa, Ob);
    }
    __syncthreads();
    cur ^= 1;
  }
#undef STAGE

  const float inv = 1.0f / lsum;
  unsigned short* yp = y + (size_t)qrow_g * 1024 + h * 64;
  #pragma unroll
  for (int c2 = 0; c2 < 4; c2++){
    uint2v da, db;
    da.x = cvtpk_bf(Oa[4 * c2 + 0] * inv, Oa[4 * c2 + 1] * inv);
    da.y = cvtpk_bf(Oa[4 * c2 + 2] * inv, Oa[4 * c2 + 3] * inv);
    *(uint2v*)&yp[8 * c2 + 4 * hi] = da;
    db.x = cvtpk_bf(Ob[4 * c2 + 0] * inv, Ob[4 * c2 + 1] * inv);
    db.y = cvtpk_bf(Ob[4 * c2 + 2] * inv, Ob[4 * c2 + 3] * inv);
    *(uint2v*)&yp[32 + 8 * c2 + 4 * hi] = db;
  }
}

// ===== launch =====
extern "C" void kernel_launch(void* const* d_in, const int* in_sizes, int n_in,
                              void* d_out, int out_size, void* d_ws, size_t ws_size,
                              hipStream_t stream)
{
  const float* x      = (const float*)d_in[0];
  const float* ln1_w  = (const float*)d_in[1];
  const float* ln1_b  = (const float*)d_in[2];
  const float* w_attn = (const float*)d_in[3];
  const float* b_attn = (const float*)d_in[4];
  const float* w_proj = (const float*)d_in[5];
  const float* b_proj = (const float*)d_in[6];
  const float* ln2_w  = (const float*)d_in[7];
  const float* ln2_b  = (const float*)d_in[8];
  const float* w_fc   = (const float*)d_in[9];
  const float* b_fc   = (const float*)d_in[10];
  const float* w_fc2  = (const float*)d_in[11];
  const float* b_fc2  = (const float*)d_in[12];

  char* ws = (char*)d_ws;
  unsigned short* wbT_attn = (unsigned short*)(ws + 0);          //  [3072][1024]
  unsigned short* wbT_proj = (unsigned short*)(ws + 6291456);    //  [1024][1024]
  unsigned short* wbT_fc   = (unsigned short*)(ws + 8388608);    //  [4096][1024]
  unsigned short* wbT_fc2  = (unsigned short*)(ws + 16777216);   //  [1024][4096]
  unsigned short* h_bf     = (unsigned short*)(ws + 25165824);   //  [8192][1024]
  unsigned short* qkv_bf   = (unsigned short*)(ws + 41943040);   //  [8192][3072]
  unsigned short* vt_bf    = (unsigned short*)(ws + 92274688);   //  [64][64][2048]
  unsigned short* g_bf     = (unsigned short*)(ws + 41943040);   //  alias qkv+vt: [8192][4096]
  unsigned short* y_bf     = (unsigned short*)(ws + 109051904);  //  [8192][1024]
  float*          x1       = (float*)(ws + 125829120);           //  [8192][1024]
  float* outf = (float*)d_out;

  wtrans_kernel<<<dim3(3072/32, 1024/32), 256, 0, stream>>>(w_attn, wbT_attn, 1024, 3072);
  wtrans_kernel<<<dim3(1024/32, 1024/32), 256, 0, stream>>>(w_proj, wbT_proj, 1024, 1024);
  wtrans_kernel<<<dim3(4096/32, 1024/32), 256, 0, stream>>>(w_fc,   wbT_fc,   1024, 4096);
  wtrans_kernel<<<dim3(1024/32, 4096/32), 256, 0, stream>>>(w_fc2,  wbT_fc2,  4096, 1024);

  // LN1: x -> h_bf
  ln_kernel<<<8192, 256, 0, stream>>>(x, ln1_w, ln1_b, h_bf);
  // qkv = h @ w_attn + b_attn   (grid = 64 m x 12 n = 768, 2 blocks/CU)
  gemm5_kernel<EPI_BF16><<<768, 256, 0, stream>>>(
      h_bf, wbT_attn, b_attn, nullptr, qkv_bf, 8192, 3072, 1024);
  // V transpose for PV operand
  vtrans_kernel<<<dim3(64, 2, 64), 256, 0, stream>>>(qkv_bf, vt_bf);
  // causal flash attention -> y_bf
  attn_kernel<<<1024, 256, 0, stream>>>(qkv_bf, vt_bf, y_bf);
  // x1 = x + y @ w_proj + b_proj   (grid = 64 m x 8 n = 512, 3 blocks/CU)
  gemm7_kernel<EPI_RESF32><<<512, 256, 0, stream>>>(
      y_bf, wbT_proj, b_proj, x, x1, 8192, 1024, 1024);
  // LN2: x1 -> h_bf
  ln_kernel<<<8192, 256, 0, stream>>>(x1, ln2_w, ln2_b, h_bf);
  // g = gelu(h2 @ w_fc + b_fc)   (grid = 64 m x 16 n = 1024, 2 blocks/CU)
  gemm5_kernel<EPI_GELU><<<1024, 256, 0, stream>>>(
      h_bf, wbT_fc, b_fc, nullptr, g_bf, 8192, 4096, 1024);
  // out = x1 + g @ w_fc2 + b_fc2   (grid = 64 m x 8 n = 512, 3 blocks/CU)
  gemm7_kernel<EPI_RESF32><<<512, 256, 0, stream>>>(
      g_bf, wbT_fc2, b_fc2, x1, outf, 8192, 1024, 4096);
}

// Round 11
// 378.572 us; speedup vs baseline: 1.0043x; 1.0043x over previous
//
#include <hip/hip_runtime.h>

// ===== types =====
typedef __attribute__((ext_vector_type(8))) short short8;       // 8 x bf16 bits
typedef __attribute__((ext_vector_type(8))) unsigned short ushort8;
typedef __attribute__((ext_vector_type(4))) float f32x4;
typedef __attribute__((ext_vector_type(16))) float f32x16;
typedef __attribute__((ext_vector_type(2))) unsigned int uint2v;
typedef unsigned int uint32;

__device__ __forceinline__ unsigned short f2bf(float f){
  union { float f; unsigned int u; } x; x.f = f;
  unsigned int u = x.u;
  u += 0x7fffu + ((u >> 16) & 1u);   // RNE
  return (unsigned short)(u >> 16);
}
__device__ __forceinline__ float bf2f(unsigned short s){
  union { float f; unsigned int u; } x; x.u = ((uint32)s) << 16; return x.f;
}

typedef __attribute__((address_space(1))) void gvoid;
typedef __attribute__((address_space(3))) void lvoid;
__device__ __forceinline__ void gload_lds16(const void* g, void* l){
  __builtin_amdgcn_global_load_lds((gvoid*)g, (lvoid*)l, 16, 0, 0);
}

__device__ __forceinline__ f32x16 mfma32(short8 a, short8 b, f32x16 c){
  return __builtin_amdgcn_mfma_f32_32x32x16_bf16(a, b, c, 0, 0, 0);
}

__device__ __forceinline__ uint32 cvtpk_bf(float lo, float hi){
  uint32 r;
  asm("v_cvt_pk_bf16_f32 %0, %1, %2" : "=v"(r) : "v"(lo), "v"(hi));
  return r;
}
__device__ __forceinline__ void plswap(uint32& a, uint32& b){
  auto r = __builtin_amdgcn_permlane32_swap(a, b, false, false);
  a = r[0]; b = r[1];
}

#if __has_builtin(__builtin_amdgcn_exp2f)
__device__ __forceinline__ float exp2g(float x){ return __builtin_amdgcn_exp2f(x); }
#else
__device__ __forceinline__ float exp2g(float x){ return exp2f(x); }
#endif
#if __has_builtin(__builtin_amdgcn_rcpf)
__device__ __forceinline__ float rcpg(float x){ return __builtin_amdgcn_rcpf(x); }
#else
__device__ __forceinline__ float rcpg(float x){ return 1.0f / x; }
#endif

// fast gelu: v - v/(1+exp2(2*log2e * u)), u = c0*(v + 0.044715 v^3)
__device__ __forceinline__ float gelu_fast(float v){
  const float u = 0.7978845608028654f * (v + 0.044715f * v * v * v);
  const float E = exp2g(2.8853900817779268f * u);
  return v - v * rcpg(1.0f + E);
}

// slot swizzle for 64B rows of 4x16B slots, 32-row read groups:
// bits [1:0] from (row>>1), bit 1 additionally XOR'd with row bit 4 so rows
// 16 apart land on different banks (32B-column model: col = 2*row + slot/2).
__device__ __forceinline__ int swz4(int row){
  return ((row >> 1) & 3) ^ (((row >> 4) & 1) << 1);
}

__device__ __forceinline__ f32x16 zero16(){
  f32x16 z;
  #pragma unroll
  for (int i = 0; i < 16; i++) z[i] = 0.0f;
  return z;
}

// ===== weight transpose + fp32->bf16: w[K][N] -> wt[N][K] =====
__global__ __launch_bounds__(256) void wtrans_kernel(
    const float* __restrict__ w, unsigned short* __restrict__ wt, int K, int N)
{
  __shared__ float tile[32][33];
  const int n0 = blockIdx.x * 32;
  const int k0 = blockIdx.y * 32;
  const int t = threadIdx.x;
  #pragma unroll
  for (int i = 0; i < 4; i++){
    const int e = t + i * 256;
    const int r = e >> 5, c = e & 31;
    tile[r][c] = w[(size_t)(k0 + r) * N + n0 + c];
  }
  __syncthreads();
  #pragma unroll
  for (int i = 0; i < 4; i++){
    const int e = t + i * 256;
    const int r = e >> 5, c = e & 31;   // r = n-local, c = k-local
    wt[(size_t)(n0 + r) * K + k0 + c] = f2bf(tile[c][r]);
  }
}

// ===== V transpose: qkv[8192][3072] (v at col 2048+h*64) -> vt[bh][64][2048] bf16 =====
__global__ __launch_bounds__(256) void vtrans_kernel(
    const unsigned short* __restrict__ qkv, unsigned short* __restrict__ vt)
{
  __shared__ unsigned short tile[32][33];
  const int bh = blockIdx.z;
  const int b = bh >> 4, h = bh & 15;
  const int t0 = blockIdx.x * 32;
  const int f0 = blockIdx.y * 32;
  const int t = threadIdx.x;
  #pragma unroll
  for (int i = 0; i < 4; i++){
    const int e = t + i * 256;
    const int r = e >> 5, c = e & 31;   // r = t-local, c = feat-local
    tile[r][c] = qkv[(size_t)(b * 2048 + t0 + r) * 3072 + 2048 + h * 64 + f0 + c];
  }
  __syncthreads();
  #pragma unroll
  for (int i = 0; i < 4; i++){
    const int e = t + i * 256;
    const int r = e >> 5, c = e & 31;   // r = feat-local, c = t-local
    vt[((size_t)bh * 64 + f0 + r) * 2048 + t0 + c] = tile[c][r];
  }
}

// ===== LayerNorm fp32 -> bf16 (row = 1024) =====
__global__ __launch_bounds__(256) void ln_kernel(
    const float* __restrict__ x, const float* __restrict__ w, const float* __restrict__ b,
    unsigned short* __restrict__ out)
{
  const int row = blockIdx.x;
  const int t = threadIdx.x;
  const float4 v = ((const float4*)(x + (size_t)row * 1024))[t];
  float s  = v.x + v.y + v.z + v.w;
  float s2 = v.x * v.x + v.y * v.y + v.z * v.z + v.w * v.w;
  #pragma unroll
  for (int off = 32; off > 0; off >>= 1){
    s  += __shfl_xor(s, off);
    s2 += __shfl_xor(s2, off);
  }
  __shared__ float ps[8];
  const int wid = t >> 6;
  if ((t & 63) == 0){ ps[wid] = s; ps[4 + wid] = s2; }
  __syncthreads();
  s  = ps[0] + ps[1] + ps[2] + ps[3];
  s2 = ps[4] + ps[5] + ps[6] + ps[7];
  const float mu  = s * (1.0f / 1024.0f);
  const float var = s2 * (1.0f / 1024.0f) - mu * mu;
  const float rs  = rsqrtf(var + 1e-5f);
  const float4 wv = ((const float4*)w)[t];
  const float4 bv = ((const float4*)b)[t];
  ushort4 ov;
  ov.x = f2bf((v.x - mu) * rs * wv.x + bv.x);
  ov.y = f2bf((v.y - mu) * rs * wv.y + bv.y);
  ov.z = f2bf((v.z - mu) * rs * wv.z + bv.z);
  ov.w = f2bf((v.w - mu) * rs * wv.w + bv.w);
  ((ushort4*)(out + (size_t)row * 1024))[t] = ov;
}

#define EPI_BF16   0
#define EPI_RESF32 1
#define EPI_GELU   2

// ===== GEMM gemm5 (mfma32): BM=128 BN=256, 2 blocks/CU (N>=2048 shapes) ====
// 4 waves (1M x 4N), per-wave 128x64 = 4 m-blocks x 2 n-blocks of 32x32.
// mfma_f32_32x32x16_bf16 halves MFMA instruction count at identical LDS
// traffic (12 ds_read_b128 per slice for 16 mfma32). BK=32 ring-3 (72KB ->
// 2 blocks/CU), counted vmcnt(6), one barrier/slice, compiler-interleaved
// body. Swizzle swz4 (incl. row-bit-4 term): 32-row fragment reads cover
// all 32 banks exactly once per 32-lane half (R10's (row>>1)&3-only swizzle
// collided rows 16 apart -> 6.3M conflicts). Inverse-swizzled global src.
template<int EPI>
__global__ __launch_bounds__(256, 2) void gemm5_kernel(
    const unsigned short* __restrict__ A,
    const unsigned short* __restrict__ BT,
    const float* __restrict__ bias,
    const float* __restrict__ res,
    void* __restrict__ outp,
    int M, int N, int K)
{
  constexpr int SLOT = 24576;   // A 8KB + B 16KB
  __shared__ __align__(16) char lds[3 * SLOT];

  const int nwg = gridDim.x;
  const int bid = blockIdx.x;
  const int wg = (bid & 7) * (nwg >> 3) + (bid >> 3);
  const int NT = N >> 8;
  const int mt = wg / NT;
  const int nti = wg - mt * NT;
  const int m0 = mt << 7;
  const int n0 = nti << 8;

  const int tid = threadIdx.x;
  const int lane = tid & 63;
  const int wid = tid >> 6;          // wave = 64-col band
  const int l31 = lane & 31;
  const int hi = lane >> 5;

  const unsigned short* aSrc[2]; int aDst[2];
  #pragma unroll
  for (int l = 0; l < 2; l++){
    const int s = l * 256 + tid;
    const int r = s >> 2, c = s & 3;
    aSrc[l] = A + (size_t)(m0 + r) * K + ((c ^ swz4(r)) << 3);
    aDst[l] = s * 16;
  }
  const unsigned short* bSrc[4]; int bDst[4];
  #pragma unroll
  for (int l = 0; l < 4; l++){
    const int s = l * 256 + tid;
    const int r = s >> 2, c = s & 3;
    bSrc[l] = BT + (size_t)(n0 + r) * K + ((c ^ swz4(r)) << 3);
    bDst[l] = 8192 + s * 16;
  }

  // fragment read offsets: A[row=mb*32+l31][chunk kh*2+hi], swizzled slot
  int aOff[4][2], bOff[2][2];
  #pragma unroll
  for (int mb = 0; mb < 4; mb++){
    const int row = mb * 32 + l31;
    #pragma unroll
    for (int kh = 0; kh < 2; kh++)
      aOff[mb][kh] = row * 64 + (((kh * 2 + hi) ^ swz4(row)) << 4);
  }
  #pragma unroll
  for (int nb = 0; nb < 2; nb++){
    const int row = wid * 64 + nb * 32 + l31;
    #pragma unroll
    for (int kh = 0; kh < 2; kh++)
      bOff[nb][kh] = 8192 + row * 64 + (((kh * 2 + hi) ^ swz4(row)) << 4);
  }

  f32x16 acc[4][2];
  #pragma unroll
  for (int i = 0; i < 4; i++)
    #pragma unroll
    for (int j = 0; j < 2; j++) acc[i][j] = zero16();

#define STAGE5(sl, slot) do { \
    gload_lds16(aSrc[0] + (size_t)(sl) * 32, lds + (slot) + aDst[0]); \
    gload_lds16(aSrc[1] + (size_t)(sl) * 32, lds + (slot) + aDst[1]); \
    gload_lds16(bSrc[0] + (size_t)(sl) * 32, lds + (slot) + bDst[0]); \
    gload_lds16(bSrc[1] + (size_t)(sl) * 32, lds + (slot) + bDst[1]); \
    gload_lds16(bSrc[2] + (size_t)(sl) * 32, lds + (slot) + bDst[2]); \
    gload_lds16(bSrc[3] + (size_t)(sl) * 32, lds + (slot) + bDst[3]); \
  } while (0)

  const int NS = K >> 5;

  STAGE5(0, 0);
  STAGE5(1, SLOT);
  asm volatile("s_waitcnt vmcnt(6)" ::: "memory");
  __builtin_amdgcn_s_barrier();
  asm volatile("" ::: "memory");

  int cs = 0, cg = 2 * SLOT;
  for (int s = 0; s < NS; s++){
    short8 aF[4][2], bF[2][2];
    #pragma unroll
    for (int mb = 0; mb < 4; mb++)
      #pragma unroll
      for (int kh = 0; kh < 2; kh++)
        aF[mb][kh] = *(const short8*)(lds + cs + aOff[mb][kh]);
    #pragma unroll
    for (int nb = 0; nb < 2; nb++)
      #pragma unroll
      for (int kh = 0; kh < 2; kh++)
        bF[nb][kh] = *(const short8*)(lds + cs + bOff[nb][kh]);
    if (s + 2 < NS) STAGE5(s + 2, cg);
    #pragma unroll
    for (int mb = 0; mb < 4; mb++)
      #pragma unroll
      for (int nb = 0; nb < 2; nb++){
        acc[mb][nb] = mfma32(aF[mb][0], bF[nb][0], acc[mb][nb]);
        acc[mb][nb] = mfma32(aF[mb][1], bF[nb][1], acc[mb][nb]);
      }

    if (s + 2 < NS){
      asm volatile("s_waitcnt vmcnt(6)" ::: "memory");
    } else if (s + 1 < NS){
      asm volatile("s_waitcnt vmcnt(0)" ::: "memory");
    }
    __builtin_amdgcn_s_barrier();
    asm volatile("" ::: "memory");

    cs += SLOT; if (cs == 3 * SLOT) cs = 0;
    cg += SLOT; if (cg == 3 * SLOT) cg = 0;
  }
#undef STAGE5

  // epilogue: C row = m0 + mb*32 + (r&3)+8*(r>>2)+4*hi, col = n-band + l31
  #pragma unroll
  for (int mb = 0; mb < 4; mb++){
    #pragma unroll
    for (int nb = 0; nb < 2; nb++){
      const int ncol = n0 + wid * 64 + nb * 32 + l31;
      const float bv = bias[ncol];
      #pragma unroll
      for (int r = 0; r < 16; r++){
        const int mrow = m0 + mb * 32 + (r & 3) + 8 * (r >> 2) + 4 * hi;
        const size_t idx = (size_t)mrow * N + ncol;
        float v = acc[mb][nb][r] + bv;
        if (EPI == EPI_RESF32){
          ((float*)outp)[idx] = v + res[idx];
        } else if (EPI == EPI_GELU){
          ((unsigned short*)outp)[idx] = f2bf(gelu_fast(v));
        } else {
          ((unsigned short*)outp)[idx] = f2bf(v);
        }
      }
    }
  }
}

// ===== GEMM gemm7 (mfma32): N=1024 shapes (proj, fc2) =====================
// BM=128, BN=128, 256 thr = 4 waves (2M x 2N), per-wave 64x64 = 2x2 blocks
// of 32x32. 8 ds_read + 4 stage loads per slice for 8 mfma32. Ring-3 48KB
// -> 3 blocks/CU, 3 waves/SIMD. Counted vmcnt(4), one barrier/slice,
// swz4 swizzle both-sides.
template<int EPI>
__global__ __launch_bounds__(256, 3) void gemm7_kernel(
    const unsigned short* __restrict__ A,
    const unsigned short* __restrict__ BT,
    const float* __restrict__ bias,
    const float* __restrict__ res,
    void* __restrict__ outp,
    int M, int N, int K)
{
  constexpr int SLOT = 16384;   // A 8KB + B 8KB
  __shared__ __align__(16) char lds[3 * SLOT];

  const int nwg = gridDim.x;
  const int bid = blockIdx.x;
  const int wg = (bid & 7) * (nwg >> 3) + (bid >> 3);
  const int NT = N >> 7;
  const int mt = wg / NT;
  const int nti = wg - mt * NT;
  const int m0 = mt << 7;
  const int n0 = nti << 7;

  const int tid = threadIdx.x;
  const int lane = tid & 63;
  const int wid = tid >> 6;
  const int wv_m = wid >> 1;     // 0..1 -> 64-row band
  const int wv_n = wid & 1;      // 0..1 -> 64-col band
  const int l31 = lane & 31;
  const int hi = lane >> 5;

  const unsigned short* aSrc[2]; int aDst[2];
  const unsigned short* bSrc[2]; int bDst[2];
  #pragma unroll
  for (int l = 0; l < 2; l++){
    const int s = l * 256 + tid;
    const int r = s >> 2, c = s & 3;
    const int co = (c ^ swz4(r)) << 3;
    aSrc[l] = A  + (size_t)(m0 + r) * K + co;
    bSrc[l] = BT + (size_t)(n0 + r) * K + co;
    aDst[l] = s * 16;
    bDst[l] = 8192 + s * 16;
  }

  int aOff[2][2], bOff[2][2];
  #pragma unroll
  for (int mb = 0; mb < 2; mb++){
    const int row = wv_m * 64 + mb * 32 + l31;
    #pragma unroll
    for (int kh = 0; kh < 2; kh++)
      aOff[mb][kh] = row * 64 + (((kh * 2 + hi) ^ swz4(row)) << 4);
  }
  #pragma unroll
  for (int nb = 0; nb < 2; nb++){
    const int row = wv_n * 64 + nb * 32 + l31;
    #pragma unroll
    for (int kh = 0; kh < 2; kh++)
      bOff[nb][kh] = 8192 + row * 64 + (((kh * 2 + hi) ^ swz4(row)) << 4);
  }

  f32x16 acc[2][2];
  #pragma unroll
  for (int i = 0; i < 2; i++)
    #pragma unroll
    for (int j = 0; j < 2; j++) acc[i][j] = zero16();

#define STAGE7(sl, slot) do { \
    gload_lds16(aSrc[0] + (size_t)(sl) * 32, lds + (slot) + aDst[0]); \
    gload_lds16(aSrc[1] + (size_t)(sl) * 32, lds + (slot) + aDst[1]); \
    gload_lds16(bSrc[0] + (size_t)(sl) * 32, lds + (slot) + bDst[0]); \
    gload_lds16(bSrc[1] + (size_t)(sl) * 32, lds + (slot) + bDst[1]); \
  } while (0)

  const int NS = K >> 5;

  STAGE7(0, 0);
  STAGE7(1, SLOT);
  asm volatile("s_waitcnt vmcnt(4)" ::: "memory");
  __builtin_amdgcn_s_barrier();
  asm volatile("" ::: "memory");

  int cs = 0, cg = 2 * SLOT;
  for (int s = 0; s < NS; s++){
    short8 aF[2][2], bF[2][2];
    #pragma unroll
    for (int mb = 0; mb < 2; mb++)
      #pragma unroll
      for (int kh = 0; kh < 2; kh++)
        aF[mb][kh] = *(const short8*)(lds + cs + aOff[mb][kh]);
    #pragma unroll
    for (int nb = 0; nb < 2; nb++)
      #pragma unroll
      for (int kh = 0; kh < 2; kh++)
        bF[nb][kh] = *(const short8*)(lds + cs + bOff[nb][kh]);
    if (s + 2 < NS) STAGE7(s + 2, cg);
    #pragma unroll
    for (int mb = 0; mb < 2; mb++)
      #pragma unroll
      for (int nb = 0; nb < 2; nb++){
        acc[mb][nb] = mfma32(aF[mb][0], bF[nb][0], acc[mb][nb]);
        acc[mb][nb] = mfma32(aF[mb][1], bF[nb][1], acc[mb][nb]);
      }

    if (s + 2 < NS){
      asm volatile("s_waitcnt vmcnt(4)" ::: "memory");
    } else if (s + 1 < NS){
      asm volatile("s_waitcnt vmcnt(0)" ::: "memory");
    }
    __builtin_amdgcn_s_barrier();
    asm volatile("" ::: "memory");

    cs += SLOT; if (cs == 3 * SLOT) cs = 0;
    cg += SLOT; if (cg == 3 * SLOT) cg = 0;
  }
#undef STAGE7

  #pragma unroll
  for (int mb = 0; mb < 2; mb++){
    #pragma unroll
    for (int nb = 0; nb < 2; nb++){
      const int ncol = n0 + wv_n * 64 + nb * 32 + l31;
      const float bv = bias[ncol];
      #pragma unroll
      for (int r = 0; r < 16; r++){
        const int mrow = m0 + wv_m * 64 + mb * 32 + (r & 3) + 8 * (r >> 2) + 4 * hi;
        const size_t idx = (size_t)mrow * N + ncol;
        float v = acc[mb][nb][r] + bv;
        if (EPI == EPI_RESF32){
          ((float*)outp)[idx] = v + res[idx];
        } else if (EPI == EPI_GELU){
          ((unsigned short*)outp)[idx] = f2bf(gelu_fast(v));
        } else {
          ((unsigned short*)outp)[idx] = f2bf(v);
        }
      }
    }
  }
}

// ===== causal flash attention (unchanged) =====
template<bool MASK>
__device__ __forceinline__ void attn_tile(
    const unsigned short* __restrict__ Kc, const unsigned short* __restrict__ Vc,
    const short8 (&qf)[4], int kvbase, int qg, int l31, int hi,
    float& m_r, float& lsum, f32x16& Oa, f32x16& Ob)
{
  f32x16 Sa = zero16();
  f32x16 Sb = zero16();
  const int xb = l31 & 7;
  #pragma unroll
  for (int kk = 0; kk < 4; kk++){
    const int x = kk * 2 + hi;
    const short8 k0 = *(const short8*)((const char*)Kc + l31 * 128 + ((x ^ xb) << 4));
    const short8 k1 = *(const short8*)((const char*)Kc + (l31 + 32) * 128 + ((x ^ xb) << 4));
    Sa = mfma32(k0, qf[kk], Sa);
    Sb = mfma32(k1, qf[kk], Sb);
  }
  if (MASK){
    #pragma unroll
    for (int r = 0; r < 16; r++){
      const int kva = kvbase + (r & 3) + 8 * (r >> 2) + 4 * hi;
      Sa[r] = (kva > qg)      ? -1e30f : Sa[r];
      Sb[r] = (kva + 32 > qg) ? -1e30f : Sb[r];
    }
  }
  float tmax = Sa[0];
  #pragma unroll
  for (int r = 1; r < 16; r++) tmax = fmaxf(tmax, Sa[r]);
  #pragma unroll
  for (int r = 0; r < 16; r++) tmax = fmaxf(tmax, Sb[r]);
  tmax = fmaxf(tmax, __shfl_xor(tmax, 32));
  if (__any(tmax > m_r + 10.0f)){
    const float mn = fmaxf(m_r, tmax);
    const float sc = exp2g(m_r - mn);
    m_r = mn;
    lsum *= sc;
    #pragma unroll
    for (int r = 0; r < 16; r++){ Oa[r] *= sc; Ob[r] *= sc; }
  }
  float rs = 0.0f;
  #pragma unroll
  for (int r = 0; r < 16; r++){
    Sa[r] = exp2g(Sa[r] - m_r); rs += Sa[r];
    Sb[r] = exp2g(Sb[r] - m_r); rs += Sb[r];
  }
  rs += __shfl_xor(rs, 32);
  lsum += rs;

  short8 pf[4];
  {
    uint32 a0 = cvtpk_bf(Sa[0], Sa[1]),   b0 = cvtpk_bf(Sa[4], Sa[5]);
    uint32 a1 = cvtpk_bf(Sa[2], Sa[3]),   b1 = cvtpk_bf(Sa[6], Sa[7]);
    plswap(a0, b0); plswap(a1, b1);
    uint32 a2 = cvtpk_bf(Sa[8], Sa[9]),   b2 = cvtpk_bf(Sa[12], Sa[13]);
    uint32 a3 = cvtpk_bf(Sa[10], Sa[11]), b3 = cvtpk_bf(Sa[14], Sa[15]);
    plswap(a2, b2); plswap(a3, b3);
    union { uint32 u[4]; short8 s; } m0, m1;
    m0.u[0] = a0; m0.u[1] = a1; m0.u[2] = b0; m0.u[3] = b1;
    m1.u[0] = a2; m1.u[1] = a3; m1.u[2] = b2; m1.u[3] = b3;
    pf[0] = m0.s; pf[1] = m1.s;
  }
  {
    uint32 a0 = cvtpk_bf(Sb[0], Sb[1]),   b0 = cvtpk_bf(Sb[4], Sb[5]);
    uint32 a1 = cvtpk_bf(Sb[2], Sb[3]),   b1 = cvtpk_bf(Sb[6], Sb[7]);
    plswap(a0, b0); plswap(a1, b1);
    uint32 a2 = cvtpk_bf(Sb[8], Sb[9]),   b2 = cvtpk_bf(Sb[12], Sb[13]);
    uint32 a3 = cvtpk_bf(Sb[10], Sb[11]), b3 = cvtpk_bf(Sb[14], Sb[15]);
    plswap(a2, b2); plswap(a3, b3);
    union { uint32 u[4]; short8 s; } m0, m1;
    m0.u[0] = a0; m0.u[1] = a1; m0.u[2] = b0; m0.u[3] = b1;
    m1.u[0] = a2; m1.u[1] = a3; m1.u[2] = b2; m1.u[3] = b3;
    pf[2] = m0.s; pf[3] = m1.s;
  }
  #pragma unroll
  for (int kk = 0; kk < 4; kk++){
    const int x = kk * 2 + hi;
    const short8 v0 = *(const short8*)((const char*)Vc + l31 * 128 + ((x ^ xb) << 4));
    const short8 v1 = *(const short8*)((const char*)Vc + (l31 + 32) * 128 + ((x ^ xb) << 4));
    Oa = mfma32(v0, pf[kk], Oa);
    Ob = mfma32(v1, pf[kk], Ob);
  }
}

__global__ __launch_bounds__(256) void attn_kernel(
    const unsigned short* __restrict__ qkv,
    const unsigned short* __restrict__ vt,
    unsigned short* __restrict__ y)
{
  __shared__ __align__(16) unsigned short Klds[2][4096];
  __shared__ __align__(16) unsigned short Vlds[2][4096];
  const int bid = blockIdx.x;
  const int bh = bid & 63;
  const int qb_i = bid >> 6;
  const int b = bh >> 4, h = bh & 15;
  const int qb0 = qb_i * 128;
  const int tid = threadIdx.x;
  const int w = tid >> 6;
  const int lane = tid & 63;
  const int l31 = lane & 31;
  const int hi = lane >> 5;

  const int qrow_g = b * 2048 + qb0 + w * 32 + l31;
  const unsigned short* qp = qkv + (size_t)qrow_g * 3072 + h * 64;
  short8 qf[4];
  #pragma unroll
  for (int kk = 0; kk < 4; kk++){
    short8 raw = *(const short8*)&qp[kk * 16 + hi * 8];
    #pragma unroll
    for (int j = 0; j < 8; j++)
      qf[kk][j] = (short)f2bf(bf2f((unsigned short)raw[j]) * 0.18033688011112042f);
  }

  const int sr = tid >> 3;
  const int ce = ((tid & 7) ^ (sr & 7)) * 8;
  const unsigned short* kb = qkv + (size_t)(b * 2048) * 3072 + 1024 + h * 64;
  const unsigned short* vb = vt + (size_t)bh * 64 * 2048;

  f32x16 Oa = zero16(), Ob = zero16();
  float m_r = -1e30f, lsum = 0.0f;
  const int qmin = qb0 + w * 32;
  const int qmax = qmin + 31;
  const int qg = qmin + l31;
  const int nkv = (qb0 >> 6) + 2;

#define STAGE(t, bb) do { \
    const size_t kro = (size_t)((t) * 64 + sr) * 3072; \
    gload_lds16(kb + kro + ce,                         (char*)&Klds[bb][0] + tid * 16); \
    gload_lds16(kb + kro + (size_t)32 * 3072 + ce,     (char*)&Klds[bb][0] + 4096 + tid * 16); \
    gload_lds16(vb + (size_t)sr * 2048 + (t) * 64 + ce,        (char*)&Vlds[bb][0] + tid * 16); \
    gload_lds16(vb + (size_t)(sr + 32) * 2048 + (t) * 64 + ce, (char*)&Vlds[bb][0] + 4096 + tid * 16); \
  } while (0)

  STAGE(0, 0);
  __syncthreads();
  int cur = 0;
  for (int kvt = 0; kvt < nkv; kvt++){
    if (kvt + 1 < nkv){
      if (cur) STAGE(kvt + 1, 0); else STAGE(kvt + 1, 1);
    }
    if (kvt * 64 <= qmax){
      if (kvt * 64 + 63 <= qmin)
        attn_tile<false>(Klds[cur], Vlds[cur], qf, kvt * 64, qg, l31, hi, m_r, lsum, Oa, Ob);
      else
        attn_tile<true >(Klds[cur], Vlds[cur], qf, kvt * 64, qg, l31, hi, m_r, lsum, Oa, Ob);
    }
    __syncthreads();
    cur ^= 1;
  }
#undef STAGE

  const float inv = 1.0f / lsum;
  unsigned short* yp = y + (size_t)qrow_g * 1024 + h * 64;
  #pragma unroll
  for (int c2 = 0; c2 < 4; c2++){
    uint2v da, db;
    da.x = cvtpk_bf(Oa[4 * c2 + 0] * inv, Oa[4 * c2 + 1] * inv);
    da.y = cvtpk_bf(Oa[4 * c2 + 2] * inv, Oa[4 * c2 + 3] * inv);
    *(uint2v*)&yp[8 * c2 + 4 * hi] = da;
    db.x = cvtpk_bf(Ob[4 * c2 + 0] * inv, Ob[4 * c2 + 1] * inv);
    db.y = cvtpk_bf(Ob[4 * c2 + 2] * inv, Ob[4 * c2 + 3] * inv);
    *(uint2v*)&yp[32 + 8 * c2 + 4 * hi] = db;
  }
}

// ===== launch =====
extern "C" void kernel_launch(void* const* d_in, const int* in_sizes, int n_in,
                              void* d_out, int out_size, void* d_ws, size_t ws_size,
                              hipStream_t stream)
{
  const float* x      = (const float*)d_in[0];
  const float* ln1_w  = (const float*)d_in[1];
  const float* ln1_b  = (const float*)d_in[2];
  const float* w_attn = (const float*)d_in[3];
  const float* b_attn = (const float*)d_in[4];
  const float* w_proj = (const float*)d_in[5];
  const float* b_proj = (const float*)d_in[6];
  const float* ln2_w  = (const float*)d_in[7];
  const float* ln2_b  = (const float*)d_in[8];
  const float* w_fc   = (const float*)d_in[9];
  const float* b_fc   = (const float*)d_in[10];
  const float* w_fc2  = (const float*)d_in[11];
  const float* b_fc2  = (const float*)d_in[12];

  char* ws = (char*)d_ws;
  unsigned short* wbT_attn = (unsigned short*)(ws + 0);          //  [3072][1024]
  unsigned short* wbT_proj = (unsigned short*)(ws + 6291456);    //  [1024][1024]
  unsigned short* wbT_fc   = (unsigned short*)(ws + 8388608);    //  [4096][1024]
  unsigned short* wbT_fc2  = (unsigned short*)(ws + 16777216);   //  [1024][4096]
  unsigned short* h_bf     = (unsigned short*)(ws + 25165824);   //  [8192][1024]
  unsigned short* qkv_bf   = (unsigned short*)(ws + 41943040);   //  [8192][3072]
  unsigned short* vt_bf    = (unsigned short*)(ws + 92274688);   //  [64][64][2048]
  unsigned short* g_bf     = (unsigned short*)(ws + 41943040);   //  alias qkv+vt: [8192][4096]
  unsigned short* y_bf     = (unsigned short*)(ws + 109051904);  //  [8192][1024]
  float*          x1       = (float*)(ws + 125829120);           //  [8192][1024]
  float* outf = (float*)d_out;

  wtrans_kernel<<<dim3(3072/32, 1024/32), 256, 0, stream>>>(w_attn, wbT_attn, 1024, 3072);
  wtrans_kernel<<<dim3(1024/32, 1024/32), 256, 0, stream>>>(w_proj, wbT_proj, 1024, 1024);
  wtrans_kernel<<<dim3(4096/32, 1024/32), 256, 0, stream>>>(w_fc,   wbT_fc,   1024, 4096);
  wtrans_kernel<<<dim3(1024/32, 4096/32), 256, 0, stream>>>(w_fc2,  wbT_fc2,  4096, 1024);

  // LN1: x -> h_bf
  ln_kernel<<<8192, 256, 0, stream>>>(x, ln1_w, ln1_b, h_bf);
  // qkv = h @ w_attn + b_attn   (grid = 64 m x 12 n = 768, 2 blocks/CU)
  gemm5_kernel<EPI_BF16><<<768, 256, 0, stream>>>(
      h_bf, wbT_attn, b_attn, nullptr, qkv_bf, 8192, 3072, 1024);
  // V transpose for PV operand
  vtrans_kernel<<<dim3(64, 2, 64), 256, 0, stream>>>(qkv_bf, vt_bf);
  // causal flash attention -> y_bf
  attn_kernel<<<1024, 256, 0, stream>>>(qkv_bf, vt_bf, y_bf);
  // x1 = x + y @ w_proj + b_proj   (grid = 64 m x 8 n = 512, 3 blocks/CU)
  gemm7_kernel<EPI_RESF32><<<512, 256, 0, stream>>>(
      y_bf, wbT_proj, b_proj, x, x1, 8192, 1024, 1024);
  // LN2: x1 -> h_bf
  ln_kernel<<<8192, 256, 0, stream>>>(x1, ln2_w, ln2_b, h_bf);
  // g = gelu(h2 @ w_fc + b_fc)   (grid = 64 m x 16 n = 1024, 2 blocks/CU)
  gemm5_kernel<EPI_GELU><<<1024, 256, 0, stream>>>(
      h_bf, wbT_fc, b_fc, nullptr, g_bf, 8192, 4096, 1024);
  // out = x1 + g @ w_fc2 + b_fc2   (grid = 64 m x 8 n = 512, 3 blocks/CU)
  gemm7_kernel<EPI_RESF32><<<512, 256, 0, stream>>>(
      g_bf, wbT_fc2, b_fc2, x1, outf, 8192, 1024, 4096);
}

// Round 12
// 353.443 us; speedup vs baseline: 1.0757x; 1.0711x over previous
//
#include <hip/hip_runtime.h>

// ===== types =====
typedef __attribute__((ext_vector_type(8))) short short8;       // 8 x bf16 bits
typedef __attribute__((ext_vector_type(8))) unsigned short ushort8;
typedef __attribute__((ext_vector_type(4))) float f32x4;
typedef __attribute__((ext_vector_type(16))) float f32x16;
typedef __attribute__((ext_vector_type(2))) unsigned int uint2v;
typedef unsigned int uint32;

__device__ __forceinline__ unsigned short f2bf(float f){
  union { float f; unsigned int u; } x; x.f = f;
  unsigned int u = x.u;
  u += 0x7fffu + ((u >> 16) & 1u);   // RNE
  return (unsigned short)(u >> 16);
}
__device__ __forceinline__ float bf2f(unsigned short s){
  union { float f; unsigned int u; } x; x.u = ((uint32)s) << 16; return x.f;
}

typedef __attribute__((address_space(1))) void gvoid;
typedef __attribute__((address_space(3))) void lvoid;
__device__ __forceinline__ void gload_lds16(const void* g, void* l){
  __builtin_amdgcn_global_load_lds((gvoid*)g, (lvoid*)l, 16, 0, 0);
}

__device__ __forceinline__ f32x4 mfma_bf16(short8 a, short8 b, f32x4 c){
  return __builtin_amdgcn_mfma_f32_16x16x32_bf16(a, b, c, 0, 0, 0);
}
__device__ __forceinline__ f32x16 mfma32(short8 a, short8 b, f32x16 c){
  return __builtin_amdgcn_mfma_f32_32x32x16_bf16(a, b, c, 0, 0, 0);
}

__device__ __forceinline__ uint32 cvtpk_bf(float lo, float hi){
  uint32 r;
  asm("v_cvt_pk_bf16_f32 %0, %1, %2" : "=v"(r) : "v"(lo), "v"(hi));
  return r;
}
__device__ __forceinline__ void plswap(uint32& a, uint32& b){
  auto r = __builtin_amdgcn_permlane32_swap(a, b, false, false);
  a = r[0]; b = r[1];
}

#if __has_builtin(__builtin_amdgcn_exp2f)
__device__ __forceinline__ float exp2g(float x){ return __builtin_amdgcn_exp2f(x); }
#else
__device__ __forceinline__ float exp2g(float x){ return exp2f(x); }
#endif
#if __has_builtin(__builtin_amdgcn_rcpf)
__device__ __forceinline__ float rcpg(float x){ return __builtin_amdgcn_rcpf(x); }
#else
__device__ __forceinline__ float rcpg(float x){ return 1.0f / x; }
#endif

// fast gelu: v - v/(1+exp2(2*log2e * u)), u = c0*(v + 0.044715 v^3)
__device__ __forceinline__ float gelu_fast(float v){
  const float u = 0.7978845608028654f * (v + 0.044715f * v * v * v);
  const float E = exp2g(2.8853900817779268f * u);
  return v - v * rcpg(1.0f + E);
}

__device__ __forceinline__ f32x16 zero16(){
  f32x16 z;
  #pragma unroll
  for (int i = 0; i < 16; i++) z[i] = 0.0f;
  return z;
}

// ===== weight transpose + fp32->bf16: w[K][N] -> wt[N][K] =====
__global__ __launch_bounds__(256) void wtrans_kernel(
    const float* __restrict__ w, unsigned short* __restrict__ wt, int K, int N)
{
  __shared__ float tile[32][33];
  const int n0 = blockIdx.x * 32;
  const int k0 = blockIdx.y * 32;
  const int t = threadIdx.x;
  #pragma unroll
  for (int i = 0; i < 4; i++){
    const int e = t + i * 256;
    const int r = e >> 5, c = e & 31;
    tile[r][c] = w[(size_t)(k0 + r) * N + n0 + c];
  }
  __syncthreads();
  #pragma unroll
  for (int i = 0; i < 4; i++){
    const int e = t + i * 256;
    const int r = e >> 5, c = e & 31;   // r = n-local, c = k-local
    wt[(size_t)(n0 + r) * K + k0 + c] = f2bf(tile[c][r]);
  }
}

// ===== V transpose: qkv[8192][3072] (v at col 2048+h*64) -> vt[bh][64][2048] bf16 =====
__global__ __launch_bounds__(256) void vtrans_kernel(
    const unsigned short* __restrict__ qkv, unsigned short* __restrict__ vt)
{
  __shared__ unsigned short tile[32][33];
  const int bh = blockIdx.z;
  const int b = bh >> 4, h = bh & 15;
  const int t0 = blockIdx.x * 32;
  const int f0 = blockIdx.y * 32;
  const int t = threadIdx.x;
  #pragma unroll
  for (int i = 0; i < 4; i++){
    const int e = t + i * 256;
    const int r = e >> 5, c = e & 31;   // r = t-local, c = feat-local
    tile[r][c] = qkv[(size_t)(b * 2048 + t0 + r) * 3072 + 2048 + h * 64 + f0 + c];
  }
  __syncthreads();
  #pragma unroll
  for (int i = 0; i < 4; i++){
    const int e = t + i * 256;
    const int r = e >> 5, c = e & 31;   // r = feat-local, c = t-local
    vt[((size_t)bh * 64 + f0 + r) * 2048 + t0 + c] = tile[c][r];
  }
}

// ===== LayerNorm fp32 -> bf16 (row = 1024) =====
__global__ __launch_bounds__(256) void ln_kernel(
    const float* __restrict__ x, const float* __restrict__ w, const float* __restrict__ b,
    unsigned short* __restrict__ out)
{
  const int row = blockIdx.x;
  const int t = threadIdx.x;
  const float4 v = ((const float4*)(x + (size_t)row * 1024))[t];
  float s  = v.x + v.y + v.z + v.w;
  float s2 = v.x * v.x + v.y * v.y + v.z * v.z + v.w * v.w;
  #pragma unroll
  for (int off = 32; off > 0; off >>= 1){
    s  += __shfl_xor(s, off);
    s2 += __shfl_xor(s2, off);
  }
  __shared__ float ps[8];
  const int wid = t >> 6;
  if ((t & 63) == 0){ ps[wid] = s; ps[4 + wid] = s2; }
  __syncthreads();
  s  = ps[0] + ps[1] + ps[2] + ps[3];
  s2 = ps[4] + ps[5] + ps[6] + ps[7];
  const float mu  = s * (1.0f / 1024.0f);
  const float var = s2 * (1.0f / 1024.0f) - mu * mu;
  const float rs  = rsqrtf(var + 1e-5f);
  const float4 wv = ((const float4*)w)[t];
  const float4 bv = ((const float4*)b)[t];
  ushort4 ov;
  ov.x = f2bf((v.x - mu) * rs * wv.x + bv.x);
  ov.y = f2bf((v.y - mu) * rs * wv.y + bv.y);
  ov.z = f2bf((v.z - mu) * rs * wv.z + bv.z);
  ov.w = f2bf((v.w - mu) * rs * wv.w + bv.w);
  ((ushort4*)(out + (size_t)row * 1024))[t] = ov;
}

#define EPI_BF16   0
#define EPI_RESF32 1
#define EPI_GELU   2

// ===== GEMM gemm5: 2-blocks/CU TLP, BM=128 BN=256 (for N>=2048 shapes) =====
// R9-proven config (0 bank conflicts): 4 waves (1M x 4N), per-wave 128x64,
// 16x16x32 MFMA (12 ds_read / 32 MFMA per slice), BK=32 ring-3 (slot 24KB,
// 72KB -> 2 blocks/CU, 2 waves/SIMD). Counted vmcnt(6), one barrier/slice,
// compiler-interleaved body, 2-way swizzle both-sides.
// NOTE: mfma32 port (R10/R11) hit a swizzle-invariant 16-cyc/read LDS
// conflict on its 32-row x 2-lane fragment reads - reverted.
template<int EPI>
__global__ __launch_bounds__(256, 2) void gemm5_kernel(
    const unsigned short* __restrict__ A,
    const unsigned short* __restrict__ BT,
    const float* __restrict__ bias,
    const float* __restrict__ res,
    void* __restrict__ outp,
    int M, int N, int K)
{
  constexpr int SLOT = 24576;   // A 8KB + B 16KB
  __shared__ __align__(16) char lds[3 * SLOT];

  const int nwg = gridDim.x;
  const int bid = blockIdx.x;
  const int wg = (bid & 7) * (nwg >> 3) + (bid >> 3);
  const int NT = N >> 8;
  const int mt = wg / NT;
  const int nti = wg - mt * NT;
  const int m0 = mt << 7;
  const int n0 = nti << 8;

  const int tid = threadIdx.x;
  const int lane = tid & 63;
  const int wid = tid >> 6;          // wave = 64-col band
  const int fr = lane & 15;
  const int fg = lane >> 4;

  const unsigned short* aSrc[2]; int aDst[2];
  #pragma unroll
  for (int l = 0; l < 2; l++){
    const int s = l * 256 + tid;
    const int r = s >> 2, c = s & 3;
    aSrc[l] = A + (size_t)(m0 + r) * K + ((c ^ ((r >> 1) & 3)) << 3);
    aDst[l] = s * 16;
  }
  const unsigned short* bSrc[4]; int bDst[4];
  #pragma unroll
  for (int l = 0; l < 4; l++){
    const int s = l * 256 + tid;
    const int r = s >> 2, c = s & 3;
    bSrc[l] = BT + (size_t)(n0 + r) * K + ((c ^ ((r >> 1) & 3)) << 3);
    bDst[l] = 8192 + s * 16;
  }

  int aOff[8], bOff[4];
  #pragma unroll
  for (int mi = 0; mi < 8; mi++){
    const int row = mi * 16 + fr;
    aOff[mi] = row * 64 + ((fg ^ ((row >> 1) & 3)) << 4);
  }
  #pragma unroll
  for (int nj = 0; nj < 4; nj++){
    const int row = wid * 64 + nj * 16 + fr;
    bOff[nj] = 8192 + row * 64 + ((fg ^ ((row >> 1) & 3)) << 4);
  }

  f32x4 acc[8][4];
  #pragma unroll
  for (int i = 0; i < 8; i++)
    #pragma unroll
    for (int j = 0; j < 4; j++) acc[i][j] = (f32x4){0.f, 0.f, 0.f, 0.f};

#define STAGE5(sl, slot) do { \
    gload_lds16(aSrc[0] + (size_t)(sl) * 32, lds + (slot) + aDst[0]); \
    gload_lds16(aSrc[1] + (size_t)(sl) * 32, lds + (slot) + aDst[1]); \
    gload_lds16(bSrc[0] + (size_t)(sl) * 32, lds + (slot) + bDst[0]); \
    gload_lds16(bSrc[1] + (size_t)(sl) * 32, lds + (slot) + bDst[1]); \
    gload_lds16(bSrc[2] + (size_t)(sl) * 32, lds + (slot) + bDst[2]); \
    gload_lds16(bSrc[3] + (size_t)(sl) * 32, lds + (slot) + bDst[3]); \
  } while (0)

  const int NS = K >> 5;

  STAGE5(0, 0);
  STAGE5(1, SLOT);
  asm volatile("s_waitcnt vmcnt(6)" ::: "memory");
  __builtin_amdgcn_s_barrier();
  asm volatile("" ::: "memory");

  int cs = 0, cg = 2 * SLOT;
  for (int s = 0; s < NS; s++){
    short8 aF[8], bF[4];
    #pragma unroll
    for (int mi = 0; mi < 8; mi++)
      aF[mi] = *(const short8*)(lds + cs + aOff[mi]);
    #pragma unroll
    for (int nj = 0; nj < 4; nj++)
      bF[nj] = *(const short8*)(lds + cs + bOff[nj]);
    if (s + 2 < NS) STAGE5(s + 2, cg);
    #pragma unroll
    for (int mi = 0; mi < 8; mi++)
      #pragma unroll
      for (int nj = 0; nj < 4; nj++)
        acc[mi][nj] = mfma_bf16(aF[mi], bF[nj], acc[mi][nj]);

    if (s + 2 < NS){
      asm volatile("s_waitcnt vmcnt(6)" ::: "memory");
    } else if (s + 1 < NS){
      asm volatile("s_waitcnt vmcnt(0)" ::: "memory");
    }
    __builtin_amdgcn_s_barrier();
    asm volatile("" ::: "memory");

    cs += SLOT; if (cs == 3 * SLOT) cs = 0;
    cg += SLOT; if (cg == 3 * SLOT) cg = 0;
  }
#undef STAGE5

  #pragma unroll
  for (int mi = 0; mi < 8; mi++){
    const int mrow = m0 + mi * 16 + fg * 4;
    #pragma unroll
    for (int nj = 0; nj < 4; nj++){
      const int ncol = n0 + wid * 64 + nj * 16 + fr;
      const float bv = bias[ncol];
      #pragma unroll
      for (int r2 = 0; r2 < 4; r2++){
        const size_t idx = (size_t)(mrow + r2) * N + ncol;
        float v = acc[mi][nj][r2] + bv;
        if (EPI == EPI_RESF32){
          ((float*)outp)[idx] = v + res[idx];
        } else if (EPI == EPI_GELU){
          ((unsigned short*)outp)[idx] = f2bf(gelu_fast(v));
        } else {
          ((unsigned short*)outp)[idx] = f2bf(v);
        }
      }
    }
  }
}

// ===== GEMM gemm7: N=1024 shapes (proj, fc2) ==============================
// R9-proven config: BM=128, BN=128, 256 thr = 4 waves (2M x 2N), per-wave
// 64x64, 16x16x32 MFMA. Slot 16KB, ring-3 = 48KB -> 3 blocks/CU, 3
// waves/SIMD. Counted vmcnt(4), one barrier/slice, 2-way swizzle.
template<int EPI>
__global__ __launch_bounds__(256, 3) void gemm7_kernel(
    const unsigned short* __restrict__ A,
    const unsigned short* __restrict__ BT,
    const float* __restrict__ bias,
    const float* __restrict__ res,
    void* __restrict__ outp,
    int M, int N, int K)
{
  constexpr int SLOT = 16384;   // A 8KB + B 8KB
  __shared__ __align__(16) char lds[3 * SLOT];

  const int nwg = gridDim.x;
  const int bid = blockIdx.x;
  const int wg = (bid & 7) * (nwg >> 3) + (bid >> 3);
  const int NT = N >> 7;
  const int mt = wg / NT;
  const int nti = wg - mt * NT;
  const int m0 = mt << 7;
  const int n0 = nti << 7;

  const int tid = threadIdx.x;
  const int lane = tid & 63;
  const int wid = tid >> 6;
  const int wv_m = wid >> 1;     // 0..1 -> 64-row band
  const int wv_n = wid & 1;      // 0..1 -> 64-col band
  const int fr = lane & 15;
  const int fg = lane >> 4;

  const unsigned short* aSrc[2]; int aDst[2];
  const unsigned short* bSrc[2]; int bDst[2];
  #pragma unroll
  for (int l = 0; l < 2; l++){
    const int s = l * 256 + tid;
    const int r = s >> 2, c = s & 3;
    const int co = (c ^ ((r >> 1) & 3)) << 3;
    aSrc[l] = A  + (size_t)(m0 + r) * K + co;
    bSrc[l] = BT + (size_t)(n0 + r) * K + co;
    aDst[l] = s * 16;
    bDst[l] = 8192 + s * 16;
  }

  int aOff[4], bOff[4];
  #pragma unroll
  for (int mi = 0; mi < 4; mi++){
    const int row = wv_m * 64 + mi * 16 + fr;
    aOff[mi] = row * 64 + ((fg ^ ((row >> 1) & 3)) << 4);
  }
  #pragma unroll
  for (int nj = 0; nj < 4; nj++){
    const int row = wv_n * 64 + nj * 16 + fr;
    bOff[nj] = 8192 + row * 64 + ((fg ^ ((row >> 1) & 3)) << 4);
  }

  f32x4 acc[4][4];
  #pragma unroll
  for (int i = 0; i < 4; i++)
    #pragma unroll
    for (int j = 0; j < 4; j++) acc[i][j] = (f32x4){0.f, 0.f, 0.f, 0.f};

#define STAGE7(sl, slot) do { \
    gload_lds16(aSrc[0] + (size_t)(sl) * 32, lds + (slot) + aDst[0]); \
    gload_lds16(aSrc[1] + (size_t)(sl) * 32, lds + (slot) + aDst[1]); \
    gload_lds16(bSrc[0] + (size_t)(sl) * 32, lds + (slot) + bDst[0]); \
    gload_lds16(bSrc[1] + (size_t)(sl) * 32, lds + (slot) + bDst[1]); \
  } while (0)

  const int NS = K >> 5;

  STAGE7(0, 0);
  STAGE7(1, SLOT);
  asm volatile("s_waitcnt vmcnt(4)" ::: "memory");
  __builtin_amdgcn_s_barrier();
  asm volatile("" ::: "memory");

  int cs = 0, cg = 2 * SLOT;
  for (int s = 0; s < NS; s++){
    short8 aF[4], bF[4];
    #pragma unroll
    for (int mi = 0; mi < 4; mi++)
      aF[mi] = *(const short8*)(lds + cs + aOff[mi]);
    #pragma unroll
    for (int nj = 0; nj < 4; nj++)
      bF[nj] = *(const short8*)(lds + cs + bOff[nj]);
    if (s + 2 < NS) STAGE7(s + 2, cg);
    #pragma unroll
    for (int mi = 0; mi < 4; mi++)
      #pragma unroll
      for (int nj = 0; nj < 4; nj++)
        acc[mi][nj] = mfma_bf16(aF[mi], bF[nj], acc[mi][nj]);

    if (s + 2 < NS){
      asm volatile("s_waitcnt vmcnt(4)" ::: "memory");
    } else if (s + 1 < NS){
      asm volatile("s_waitcnt vmcnt(0)" ::: "memory");
    }
    __builtin_amdgcn_s_barrier();
    asm volatile("" ::: "memory");

    cs += SLOT; if (cs == 3 * SLOT) cs = 0;
    cg += SLOT; if (cg == 3 * SLOT) cg = 0;
  }
#undef STAGE7

  #pragma unroll
  for (int mi = 0; mi < 4; mi++){
    const int mrow = m0 + wv_m * 64 + mi * 16 + fg * 4;
    #pragma unroll
    for (int nj = 0; nj < 4; nj++){
      const int ncol = n0 + wv_n * 64 + nj * 16 + fr;
      const float bv = bias[ncol];
      #pragma unroll
      for (int r2 = 0; r2 < 4; r2++){
        const size_t idx = (size_t)(mrow + r2) * N + ncol;
        float v = acc[mi][nj][r2] + bv;
        if (EPI == EPI_RESF32){
          ((float*)outp)[idx] = v + res[idx];
        } else if (EPI == EPI_GELU){
          ((unsigned short*)outp)[idx] = f2bf(gelu_fast(v));
        } else {
          ((unsigned short*)outp)[idx] = f2bf(v);
        }
      }
    }
  }
}

// ===== causal flash attention =====
template<bool MASK>
__device__ __forceinline__ void attn_tile(
    const unsigned short* __restrict__ Kc, const unsigned short* __restrict__ Vc,
    const short8 (&qf)[4], int kvbase, int qg, int l31, int hi,
    float& m_r, float& lsum, f32x16& Oa, f32x16& Ob)
{
  f32x16 Sa = zero16();
  f32x16 Sb = zero16();
  const int xb = l31 & 7;
  #pragma unroll
  for (int kk = 0; kk < 4; kk++){
    const int x = kk * 2 + hi;
    const short8 k0 = *(const short8*)((const char*)Kc + l31 * 128 + ((x ^ xb) << 4));
    const short8 k1 = *(const short8*)((const char*)Kc + (l31 + 32) * 128 + ((x ^ xb) << 4));
    Sa = mfma32(k0, qf[kk], Sa);
    Sb = mfma32(k1, qf[kk], Sb);
  }
  if (MASK){
    #pragma unroll
    for (int r = 0; r < 16; r++){
      const int kva = kvbase + (r & 3) + 8 * (r >> 2) + 4 * hi;
      Sa[r] = (kva > qg)      ? -1e30f : Sa[r];
      Sb[r] = (kva + 32 > qg) ? -1e30f : Sb[r];
    }
  }
  float tmax = Sa[0];
  #pragma unroll
  for (int r = 1; r < 16; r++) tmax = fmaxf(tmax, Sa[r]);
  #pragma unroll
  for (int r = 0; r < 16; r++) tmax = fmaxf(tmax, Sb[r]);
  tmax = fmaxf(tmax, __shfl_xor(tmax, 32));
  if (__any(tmax > m_r + 10.0f)){
    const float mn = fmaxf(m_r, tmax);
    const float sc = exp2g(m_r - mn);
    m_r = mn;
    lsum *= sc;
    #pragma unroll
    for (int r = 0; r < 16; r++){ Oa[r] *= sc; Ob[r] *= sc; }
  }
  float rs = 0.0f;
  #pragma unroll
  for (int r = 0; r < 16; r++){
    Sa[r] = exp2g(Sa[r] - m_r); rs += Sa[r];
    Sb[r] = exp2g(Sb[r] - m_r); rs += Sb[r];
  }
  rs += __shfl_xor(rs, 32);
  lsum += rs;

  short8 pf[4];
  {
    uint32 a0 = cvtpk_bf(Sa[0], Sa[1]),   b0 = cvtpk_bf(Sa[4], Sa[5]);
    uint32 a1 = cvtpk_bf(Sa[2], Sa[3]),   b1 = cvtpk_bf(Sa[6], Sa[7]);
    plswap(a0, b0); plswap(a1, b1);
    uint32 a2 = cvtpk_bf(Sa[8], Sa[9]),   b2 = cvtpk_bf(Sa[12], Sa[13]);
    uint32 a3 = cvtpk_bf(Sa[10], Sa[11]), b3 = cvtpk_bf(Sa[14], Sa[15]);
    plswap(a2, b2); plswap(a3, b3);
    union { uint32 u[4]; short8 s; } m0, m1;
    m0.u[0] = a0; m0.u[1] = a1; m0.u[2] = b0; m0.u[3] = b1;
    m1.u[0] = a2; m1.u[1] = a3; m1.u[2] = b2; m1.u[3] = b3;
    pf[0] = m0.s; pf[1] = m1.s;
  }
  {
    uint32 a0 = cvtpk_bf(Sb[0], Sb[1]),   b0 = cvtpk_bf(Sb[4], Sb[5]);
    uint32 a1 = cvtpk_bf(Sb[2], Sb[3]),   b1 = cvtpk_bf(Sb[6], Sb[7]);
    plswap(a0, b0); plswap(a1, b1);
    uint32 a2 = cvtpk_bf(Sb[8], Sb[9]),   b2 = cvtpk_bf(Sb[12], Sb[13]);
    uint32 a3 = cvtpk_bf(Sb[10], Sb[11]), b3 = cvtpk_bf(Sb[14], Sb[15]);
    plswap(a2, b2); plswap(a3, b3);
    union { uint32 u[4]; short8 s; } m0, m1;
    m0.u[0] = a0; m0.u[1] = a1; m0.u[2] = b0; m0.u[3] = b1;
    m1.u[0] = a2; m1.u[1] = a3; m1.u[2] = b2; m1.u[3] = b3;
    pf[2] = m0.s; pf[3] = m1.s;
  }
  #pragma unroll
  for (int kk = 0; kk < 4; kk++){
    const int x = kk * 2 + hi;
    const short8 v0 = *(const short8*)((const char*)Vc + l31 * 128 + ((x ^ xb) << 4));
    const short8 v1 = *(const short8*)((const char*)Vc + (l31 + 32) * 128 + ((x ^ xb) << 4));
    Oa = mfma32(v0, pf[kk], Oa);
    Ob = mfma32(v1, pf[kk], Ob);
  }
}

__global__ __launch_bounds__(256) void attn_kernel(
    const unsigned short* __restrict__ qkv,
    const unsigned short* __restrict__ vt,
    unsigned short* __restrict__ y)
{
  __shared__ __align__(16) unsigned short Klds[2][4096];
  __shared__ __align__(16) unsigned short Vlds[2][4096];
  const int bid = blockIdx.x;
  const int bh = bid & 63;
  const int qb_i = 15 - (bid >> 6);   // heavy q-tiles first (LPT scheduling:
                                      // qb_i=15 runs 17 KV tiles, qb_i=0 runs 2)
  const int b = bh >> 4, h = bh & 15;
  const int qb0 = qb_i * 128;
  const int tid = threadIdx.x;
  const int w = tid >> 6;
  const int lane = tid & 63;
  const int l31 = lane & 31;
  const int hi = lane >> 5;

  const int qrow_g = b * 2048 + qb0 + w * 32 + l31;
  const unsigned short* qp = qkv + (size_t)qrow_g * 3072 + h * 64;
  short8 qf[4];
  #pragma unroll
  for (int kk = 0; kk < 4; kk++){
    short8 raw = *(const short8*)&qp[kk * 16 + hi * 8];
    #pragma unroll
    for (int j = 0; j < 8; j++)
      qf[kk][j] = (short)f2bf(bf2f((unsigned short)raw[j]) * 0.18033688011112042f);
  }

  const int sr = tid >> 3;
  const int ce = ((tid & 7) ^ (sr & 7)) * 8;
  const unsigned short* kb = qkv + (size_t)(b * 2048) * 3072 + 1024 + h * 64;
  const unsigned short* vb = vt + (size_t)bh * 64 * 2048;

  f32x16 Oa = zero16(), Ob = zero16();
  float m_r = -1e30f, lsum = 0.0f;
  const int qmin = qb0 + w * 32;
  const int qmax = qmin + 31;
  const int qg = qmin + l31;
  const int nkv = (qb0 >> 6) + 2;

#define STAGE(t, bb) do { \
    const size_t kro = (size_t)((t) * 64 + sr) * 3072; \
    gload_lds16(kb + kro + ce,                         (char*)&Klds[bb][0] + tid * 16); \
    gload_lds16(kb + kro + (size_t)32 * 3072 + ce,     (char*)&Klds[bb][0] + 4096 + tid * 16); \
    gload_lds16(vb + (size_t)sr * 2048 + (t) * 64 + ce,        (char*)&Vlds[bb][0] + tid * 16); \
    gload_lds16(vb + (size_t)(sr + 32) * 2048 + (t) * 64 + ce, (char*)&Vlds[bb][0] + 4096 + tid * 16); \
  } while (0)

  STAGE(0, 0);
  __syncthreads();
  int cur = 0;
  for (int kvt = 0; kvt < nkv; kvt++){
    if (kvt + 1 < nkv){
      if (cur) STAGE(kvt + 1, 0); else STAGE(kvt + 1, 1);
    }
    if (kvt * 64 <= qmax){
      if (kvt * 64 + 63 <= qmin)
        attn_tile<false>(Klds[cur], Vlds[cur], qf, kvt * 64, qg, l31, hi, m_r, lsum, Oa, Ob);
      else
        attn_tile<true >(Klds[cur], Vlds[cur], qf, kvt * 64, qg, l31, hi, m_r, lsum, Oa, Ob);
    }
    __syncthreads();
    cur ^= 1;
  }
#undef STAGE

  const float inv = 1.0f / lsum;
  unsigned short* yp = y + (size_t)qrow_g * 1024 + h * 64;
  #pragma unroll
  for (int c2 = 0; c2 < 4; c2++){
    uint2v da, db;
    da.x = cvtpk_bf(Oa[4 * c2 + 0] * inv, Oa[4 * c2 + 1] * inv);
    da.y = cvtpk_bf(Oa[4 * c2 + 2] * inv, Oa[4 * c2 + 3] * inv);
    *(uint2v*)&yp[8 * c2 + 4 * hi] = da;
    db.x = cvtpk_bf(Ob[4 * c2 + 0] * inv, Ob[4 * c2 + 1] * inv);
    db.y = cvtpk_bf(Ob[4 * c2 + 2] * inv, Ob[4 * c2 + 3] * inv);
    *(uint2v*)&yp[32 + 8 * c2 + 4 * hi] = db;
  }
}

// ===== launch =====
extern "C" void kernel_launch(void* const* d_in, const int* in_sizes, int n_in,
                              void* d_out, int out_size, void* d_ws, size_t ws_size,
                              hipStream_t stream)
{
  const float* x      = (const float*)d_in[0];
  const float* ln1_w  = (const float*)d_in[1];
  const float* ln1_b  = (const float*)d_in[2];
  const float* w_attn = (const float*)d_in[3];
  const float* b_attn = (const float*)d_in[4];
  const float* w_proj = (const float*)d_in[5];
  const float* b_proj = (const float*)d_in[6];
  const float* ln2_w  = (const float*)d_in[7];
  const float* ln2_b  = (const float*)d_in[8];
  const float* w_fc   = (const float*)d_in[9];
  const float* b_fc   = (const float*)d_in[10];
  const float* w_fc2  = (const float*)d_in[11];
  const float* b_fc2  = (const float*)d_in[12];

  char* ws = (char*)d_ws;
  unsigned short* wbT_attn = (unsigned short*)(ws + 0);          //  [3072][1024]
  unsigned short* wbT_proj = (unsigned short*)(ws + 6291456);    //  [1024][1024]
  unsigned short* wbT_fc   = (unsigned short*)(ws + 8388608);    //  [4096][1024]
  unsigned short* wbT_fc2  = (unsigned short*)(ws + 16777216);   //  [1024][4096]
  unsigned short* h_bf     = (unsigned short*)(ws + 25165824);   //  [8192][1024]
  unsigned short* qkv_bf   = (unsigned short*)(ws + 41943040);   //  [8192][3072]
  unsigned short* vt_bf    = (unsigned short*)(ws + 92274688);   //  [64][64][2048]
  unsigned short* g_bf     = (unsigned short*)(ws + 41943040);   //  alias qkv+vt: [8192][4096]
  unsigned short* y_bf     = (unsigned short*)(ws + 109051904);  //  [8192][1024]
  float*          x1       = (float*)(ws + 125829120);           //  [8192][1024]
  float* outf = (float*)d_out;

  wtrans_kernel<<<dim3(3072/32, 1024/32), 256, 0, stream>>>(w_attn, wbT_attn, 1024, 3072);
  wtrans_kernel<<<dim3(1024/32, 1024/32), 256, 0, stream>>>(w_proj, wbT_proj, 1024, 1024);
  wtrans_kernel<<<dim3(4096/32, 1024/32), 256, 0, stream>>>(w_fc,   wbT_fc,   1024, 4096);
  wtrans_kernel<<<dim3(1024/32, 4096/32), 256, 0, stream>>>(w_fc2,  wbT_fc2,  4096, 1024);

  // LN1: x -> h_bf
  ln_kernel<<<8192, 256, 0, stream>>>(x, ln1_w, ln1_b, h_bf);
  // qkv = h @ w_attn + b_attn   (grid = 64 m x 12 n = 768, 2 blocks/CU)
  gemm5_kernel<EPI_BF16><<<768, 256, 0, stream>>>(
      h_bf, wbT_attn, b_attn, nullptr, qkv_bf, 8192, 3072, 1024);
  // V transpose for PV operand
  vtrans_kernel<<<dim3(64, 2, 64), 256, 0, stream>>>(qkv_bf, vt_bf);
  // causal flash attention -> y_bf  (heavy-first LPT ordering)
  attn_kernel<<<1024, 256, 0, stream>>>(qkv_bf, vt_bf, y_bf);
  // x1 = x + y @ w_proj + b_proj   (grid = 64 m x 8 n = 512, 3 blocks/CU)
  gemm7_kernel<EPI_RESF32><<<512, 256, 0, stream>>>(
      y_bf, wbT_proj, b_proj, x, x1, 8192, 1024, 1024);
  // LN2: x1 -> h_bf
  ln_kernel<<<8192, 256, 0, stream>>>(x1, ln2_w, ln2_b, h_bf);
  // g = gelu(h2 @ w_fc + b_fc)   (grid = 64 m x 16 n = 1024, 2 blocks/CU)
  gemm5_kernel<EPI_GELU><<<1024, 256, 0, stream>>>(
      h_bf, wbT_fc, b_fc, nullptr, g_bf, 8192, 4096, 1024);
  // out = x1 + g @ w_fc2 + b_fc2   (grid = 64 m x 8 n = 512, 3 blocks/CU)
  gemm7_kernel<EPI_RESF32><<<512, 256, 0, stream>>>(
      g_bf, wbT_fc2, b_fc2, x1, outf, 8192, 1024, 4096);
}

// Round 13
// 343.218 us; speedup vs baseline: 1.1077x; 1.0298x over previous
//
#include <hip/hip_runtime.h>

// ===== types =====
typedef __attribute__((ext_vector_type(8))) short short8;       // 8 x bf16 bits
typedef __attribute__((ext_vector_type(8))) unsigned short ushort8;
typedef __attribute__((ext_vector_type(4))) float f32x4;
typedef __attribute__((ext_vector_type(16))) float f32x16;
typedef __attribute__((ext_vector_type(2))) unsigned int uint2v;
typedef unsigned int uint32;

__device__ __forceinline__ unsigned short f2bf(float f){
  union { float f; unsigned int u; } x; x.f = f;
  unsigned int u = x.u;
  u += 0x7fffu + ((u >> 16) & 1u);   // RNE
  return (unsigned short)(u >> 16);
}
__device__ __forceinline__ float bf2f(unsigned short s){
  union { float f; unsigned int u; } x; x.u = ((uint32)s) << 16; return x.f;
}

typedef __attribute__((address_space(1))) void gvoid;
typedef __attribute__((address_space(3))) void lvoid;
__device__ __forceinline__ void gload_lds16(const void* g, void* l){
  __builtin_amdgcn_global_load_lds((gvoid*)g, (lvoid*)l, 16, 0, 0);
}

__device__ __forceinline__ f32x4 mfma_bf16(short8 a, short8 b, f32x4 c){
  return __builtin_amdgcn_mfma_f32_16x16x32_bf16(a, b, c, 0, 0, 0);
}
__device__ __forceinline__ f32x16 mfma32(short8 a, short8 b, f32x16 c){
  return __builtin_amdgcn_mfma_f32_32x32x16_bf16(a, b, c, 0, 0, 0);
}

__device__ __forceinline__ uint32 cvtpk_bf(float lo, float hi){
  uint32 r;
  asm("v_cvt_pk_bf16_f32 %0, %1, %2" : "=v"(r) : "v"(lo), "v"(hi));
  return r;
}
__device__ __forceinline__ void plswap(uint32& a, uint32& b){
  auto r = __builtin_amdgcn_permlane32_swap(a, b, false, false);
  a = r[0]; b = r[1];
}

#if __has_builtin(__builtin_amdgcn_exp2f)
__device__ __forceinline__ float exp2g(float x){ return __builtin_amdgcn_exp2f(x); }
#else
__device__ __forceinline__ float exp2g(float x){ return exp2f(x); }
#endif
#if __has_builtin(__builtin_amdgcn_rcpf)
__device__ __forceinline__ float rcpg(float x){ return __builtin_amdgcn_rcpf(x); }
#else
__device__ __forceinline__ float rcpg(float x){ return 1.0f / x; }
#endif

// fast gelu: v - v/(1+exp2(2*log2e * u)), u = c0*(v + 0.044715 v^3)
__device__ __forceinline__ float gelu_fast(float v){
  const float u = 0.7978845608028654f * (v + 0.044715f * v * v * v);
  const float E = exp2g(2.8853900817779268f * u);
  return v - v * rcpg(1.0f + E);
}

__device__ __forceinline__ f32x16 zero16(){
  f32x16 z;
  #pragma unroll
  for (int i = 0; i < 16; i++) z[i] = 0.0f;
  return z;
}

// ===== merged weight transpose + fp32->bf16 for all 4 weights =============
// w[K][N] -> wt[N][K]; blockIdx ranges select the matrix (saves 3 launches).
__global__ __launch_bounds__(256) void wtrans_all_kernel(
    const float* __restrict__ w0, unsigned short* __restrict__ t0,  // attn 1024x3072
    const float* __restrict__ w1, unsigned short* __restrict__ t1,  // proj 1024x1024
    const float* __restrict__ w2, unsigned short* __restrict__ t2,  // fc   1024x4096
    const float* __restrict__ w3, unsigned short* __restrict__ t3)  // fc2  4096x1024
{
  __shared__ float tile[32][33];
  const int bt = blockIdx.x;
  const float* w; unsigned short* wt; int K, N, ti;
  if (bt < 3072)      { w = w0; wt = t0; K = 1024; N = 3072; ti = bt; }
  else if (bt < 4096) { w = w1; wt = t1; K = 1024; N = 1024; ti = bt - 3072; }
  else if (bt < 8192) { w = w2; wt = t2; K = 1024; N = 4096; ti = bt - 4096; }
  else                { w = w3; wt = t3; K = 4096; N = 1024; ti = bt - 8192; }
  const int nbx = N >> 5;
  const int n0 = (ti % nbx) << 5;
  const int k0 = (ti / nbx) << 5;
  const int t = threadIdx.x;
  #pragma unroll
  for (int i = 0; i < 4; i++){
    const int e = t + i * 256;
    const int r = e >> 5, c = e & 31;
    tile[r][c] = w[(size_t)(k0 + r) * N + n0 + c];
  }
  __syncthreads();
  #pragma unroll
  for (int i = 0; i < 4; i++){
    const int e = t + i * 256;
    const int r = e >> 5, c = e & 31;   // r = n-local, c = k-local
    wt[(size_t)(n0 + r) * K + k0 + c] = f2bf(tile[c][r]);
  }
}

// ===== V transpose: qkv[8192][3072] (v at col 2048+h*64) -> vt[bh][64][2048] bf16 =====
__global__ __launch_bounds__(256) void vtrans_kernel(
    const unsigned short* __restrict__ qkv, unsigned short* __restrict__ vt)
{
  __shared__ unsigned short tile[32][33];
  const int bh = blockIdx.z;
  const int b = bh >> 4, h = bh & 15;
  const int t0 = blockIdx.x * 32;
  const int f0 = blockIdx.y * 32;
  const int t = threadIdx.x;
  #pragma unroll
  for (int i = 0; i < 4; i++){
    const int e = t + i * 256;
    const int r = e >> 5, c = e & 31;   // r = t-local, c = feat-local
    tile[r][c] = qkv[(size_t)(b * 2048 + t0 + r) * 3072 + 2048 + h * 64 + f0 + c];
  }
  __syncthreads();
  #pragma unroll
  for (int i = 0; i < 4; i++){
    const int e = t + i * 256;
    const int r = e >> 5, c = e & 31;   // r = feat-local, c = t-local
    vt[((size_t)bh * 64 + f0 + r) * 2048 + t0 + c] = tile[c][r];
  }
}

// ===== LayerNorm fp32 -> bf16 (row = 1024) =====
__global__ __launch_bounds__(256) void ln_kernel(
    const float* __restrict__ x, const float* __restrict__ w, const float* __restrict__ b,
    unsigned short* __restrict__ out)
{
  const int row = blockIdx.x;
  const int t = threadIdx.x;
  const float4 v = ((const float4*)(x + (size_t)row * 1024))[t];
  float s  = v.x + v.y + v.z + v.w;
  float s2 = v.x * v.x + v.y * v.y + v.z * v.z + v.w * v.w;
  #pragma unroll
  for (int off = 32; off > 0; off >>= 1){
    s  += __shfl_xor(s, off);
    s2 += __shfl_xor(s2, off);
  }
  __shared__ float ps[8];
  const int wid = t >> 6;
  if ((t & 63) == 0){ ps[wid] = s; ps[4 + wid] = s2; }
  __syncthreads();
  s  = ps[0] + ps[1] + ps[2] + ps[3];
  s2 = ps[4] + ps[5] + ps[6] + ps[7];
  const float mu  = s * (1.0f / 1024.0f);
  const float var = s2 * (1.0f / 1024.0f) - mu * mu;
  const float rs  = rsqrtf(var + 1e-5f);
  const float4 wv = ((const float4*)w)[t];
  const float4 bv = ((const float4*)b)[t];
  ushort4 ov;
  ov.x = f2bf((v.x - mu) * rs * wv.x + bv.x);
  ov.y = f2bf((v.y - mu) * rs * wv.y + bv.y);
  ov.z = f2bf((v.z - mu) * rs * wv.z + bv.z);
  ov.w = f2bf((v.w - mu) * rs * wv.w + bv.w);
  ((ushort4*)(out + (size_t)row * 1024))[t] = ov;
}

// ===== LayerNorm bf16 -> bf16 (row = 1024), for x1 stored as bf16 =====
__global__ __launch_bounds__(256) void ln_bf16_kernel(
    const unsigned short* __restrict__ x, const float* __restrict__ w,
    const float* __restrict__ b, unsigned short* __restrict__ out)
{
  const int row = blockIdx.x;
  const int t = threadIdx.x;
  const ushort4 raw = ((const ushort4*)(x + (size_t)row * 1024))[t];
  const float v0 = bf2f(raw.x), v1 = bf2f(raw.y), v2 = bf2f(raw.z), v3 = bf2f(raw.w);
  float s  = v0 + v1 + v2 + v3;
  float s2 = v0 * v0 + v1 * v1 + v2 * v2 + v3 * v3;
  #pragma unroll
  for (int off = 32; off > 0; off >>= 1){
    s  += __shfl_xor(s, off);
    s2 += __shfl_xor(s2, off);
  }
  __shared__ float ps[8];
  const int wid = t >> 6;
  if ((t & 63) == 0){ ps[wid] = s; ps[4 + wid] = s2; }
  __syncthreads();
  s  = ps[0] + ps[1] + ps[2] + ps[3];
  s2 = ps[4] + ps[5] + ps[6] + ps[7];
  const float mu  = s * (1.0f / 1024.0f);
  const float var = s2 * (1.0f / 1024.0f) - mu * mu;
  const float rs  = rsqrtf(var + 1e-5f);
  const float4 wv = ((const float4*)w)[t];
  const float4 bv = ((const float4*)b)[t];
  ushort4 ov;
  ov.x = f2bf((v0 - mu) * rs * wv.x + bv.x);
  ov.y = f2bf((v1 - mu) * rs * wv.y + bv.y);
  ov.z = f2bf((v2 - mu) * rs * wv.z + bv.z);
  ov.w = f2bf((v3 - mu) * rs * wv.w + bv.w);
  ((ushort4*)(out + (size_t)row * 1024))[t] = ov;
}

#define EPI_BF16        0   // out bf16 = v
#define EPI_GELU        1   // out bf16 = gelu(v)
#define EPI_RESF_OBF    2   // out bf16 = v + res(f32)   [proj -> x1 bf16]
#define EPI_RESBF_OF32  3   // out f32  = v + res(bf16)  [fc2 -> final out]

template<int EPI>
__device__ __forceinline__ void epi_store(void* outp, const void* res,
                                          size_t idx, float v){
  if (EPI == EPI_RESF_OBF){
    ((unsigned short*)outp)[idx] = f2bf(v + ((const float*)res)[idx]);
  } else if (EPI == EPI_RESBF_OF32){
    ((float*)outp)[idx] = v + bf2f(((const unsigned short*)res)[idx]);
  } else if (EPI == EPI_GELU){
    ((unsigned short*)outp)[idx] = f2bf(gelu_fast(v));
  } else {
    ((unsigned short*)outp)[idx] = f2bf(v);
  }
}

// ===== GEMM gemm5: 2-blocks/CU TLP, BM=128 BN=256 (for N>=2048 shapes) =====
// R9-proven config (0 bank conflicts): 4 waves (1M x 4N), per-wave 128x64,
// 16x16x32 MFMA (12 ds_read / 32 MFMA per slice), BK=32 ring-3 (slot 24KB,
// 72KB -> 2 blocks/CU, 2 waves/SIMD). Counted vmcnt(6), one barrier/slice,
// compiler-interleaved body, 2-way swizzle both-sides.
template<int EPI>
__global__ __launch_bounds__(256, 2) void gemm5_kernel(
    const unsigned short* __restrict__ A,
    const unsigned short* __restrict__ BT,
    const float* __restrict__ bias,
    const void* __restrict__ res,
    void* __restrict__ outp,
    int M, int N, int K)
{
  constexpr int SLOT = 24576;   // A 8KB + B 16KB
  __shared__ __align__(16) char lds[3 * SLOT];

  const int nwg = gridDim.x;
  const int bid = blockIdx.x;
  const int wg = (bid & 7) * (nwg >> 3) + (bid >> 3);
  const int NT = N >> 8;
  const int mt = wg / NT;
  const int nti = wg - mt * NT;
  const int m0 = mt << 7;
  const int n0 = nti << 8;

  const int tid = threadIdx.x;
  const int lane = tid & 63;
  const int wid = tid >> 6;          // wave = 64-col band
  const int fr = lane & 15;
  const int fg = lane >> 4;

  const unsigned short* aSrc[2]; int aDst[2];
  #pragma unroll
  for (int l = 0; l < 2; l++){
    const int s = l * 256 + tid;
    const int r = s >> 2, c = s & 3;
    aSrc[l] = A + (size_t)(m0 + r) * K + ((c ^ ((r >> 1) & 3)) << 3);
    aDst[l] = s * 16;
  }
  const unsigned short* bSrc[4]; int bDst[4];
  #pragma unroll
  for (int l = 0; l < 4; l++){
    const int s = l * 256 + tid;
    const int r = s >> 2, c = s & 3;
    bSrc[l] = BT + (size_t)(n0 + r) * K + ((c ^ ((r >> 1) & 3)) << 3);
    bDst[l] = 8192 + s * 16;
  }

  int aOff[8], bOff[4];
  #pragma unroll
  for (int mi = 0; mi < 8; mi++){
    const int row = mi * 16 + fr;
    aOff[mi] = row * 64 + ((fg ^ ((row >> 1) & 3)) << 4);
  }
  #pragma unroll
  for (int nj = 0; nj < 4; nj++){
    const int row = wid * 64 + nj * 16 + fr;
    bOff[nj] = 8192 + row * 64 + ((fg ^ ((row >> 1) & 3)) << 4);
  }

  f32x4 acc[8][4];
  #pragma unroll
  for (int i = 0; i < 8; i++)
    #pragma unroll
    for (int j = 0; j < 4; j++) acc[i][j] = (f32x4){0.f, 0.f, 0.f, 0.f};

#define STAGE5(sl, slot) do { \
    gload_lds16(aSrc[0] + (size_t)(sl) * 32, lds + (slot) + aDst[0]); \
    gload_lds16(aSrc[1] + (size_t)(sl) * 32, lds + (slot) + aDst[1]); \
    gload_lds16(bSrc[0] + (size_t)(sl) * 32, lds + (slot) + bDst[0]); \
    gload_lds16(bSrc[1] + (size_t)(sl) * 32, lds + (slot) + bDst[1]); \
    gload_lds16(bSrc[2] + (size_t)(sl) * 32, lds + (slot) + bDst[2]); \
    gload_lds16(bSrc[3] + (size_t)(sl) * 32, lds + (slot) + bDst[3]); \
  } while (0)

  const int NS = K >> 5;

  STAGE5(0, 0);
  STAGE5(1, SLOT);
  asm volatile("s_waitcnt vmcnt(6)" ::: "memory");
  __builtin_amdgcn_s_barrier();
  asm volatile("" ::: "memory");

  int cs = 0, cg = 2 * SLOT;
  for (int s = 0; s < NS; s++){
    short8 aF[8], bF[4];
    #pragma unroll
    for (int mi = 0; mi < 8; mi++)
      aF[mi] = *(const short8*)(lds + cs + aOff[mi]);
    #pragma unroll
    for (int nj = 0; nj < 4; nj++)
      bF[nj] = *(const short8*)(lds + cs + bOff[nj]);
    if (s + 2 < NS) STAGE5(s + 2, cg);
    #pragma unroll
    for (int mi = 0; mi < 8; mi++)
      #pragma unroll
      for (int nj = 0; nj < 4; nj++)
        acc[mi][nj] = mfma_bf16(aF[mi], bF[nj], acc[mi][nj]);

    if (s + 2 < NS){
      asm volatile("s_waitcnt vmcnt(6)" ::: "memory");
    } else if (s + 1 < NS){
      asm volatile("s_waitcnt vmcnt(0)" ::: "memory");
    }
    __builtin_amdgcn_s_barrier();
    asm volatile("" ::: "memory");

    cs += SLOT; if (cs == 3 * SLOT) cs = 0;
    cg += SLOT; if (cg == 3 * SLOT) cg = 0;
  }
#undef STAGE5

  #pragma unroll
  for (int mi = 0; mi < 8; mi++){
    const int mrow = m0 + mi * 16 + fg * 4;
    #pragma unroll
    for (int nj = 0; nj < 4; nj++){
      const int ncol = n0 + wid * 64 + nj * 16 + fr;
      const float bv = bias[ncol];
      #pragma unroll
      for (int r2 = 0; r2 < 4; r2++){
        const size_t idx = (size_t)(mrow + r2) * N + ncol;
        epi_store<EPI>(outp, res, idx, acc[mi][nj][r2] + bv);
      }
    }
  }
}

// ===== GEMM gemm7: N=1024 shapes (proj, fc2) ==============================
// R9-proven config: BM=128, BN=128, 256 thr = 4 waves (2M x 2N), per-wave
// 64x64, 16x16x32 MFMA. Slot 16KB, ring-3 = 48KB -> 3 blocks/CU. Counted
// vmcnt(4), one barrier/slice, 2-way swizzle.
template<int EPI>
__global__ __launch_bounds__(256, 3) void gemm7_kernel(
    const unsigned short* __restrict__ A,
    const unsigned short* __restrict__ BT,
    const float* __restrict__ bias,
    const void* __restrict__ res,
    void* __restrict__ outp,
    int M, int N, int K)
{
  constexpr int SLOT = 16384;   // A 8KB + B 8KB
  __shared__ __align__(16) char lds[3 * SLOT];

  const int nwg = gridDim.x;
  const int bid = blockIdx.x;
  const int wg = (bid & 7) * (nwg >> 3) + (bid >> 3);
  const int NT = N >> 7;
  const int mt = wg / NT;
  const int nti = wg - mt * NT;
  const int m0 = mt << 7;
  const int n0 = nti << 7;

  const int tid = threadIdx.x;
  const int lane = tid & 63;
  const int wid = tid >> 6;
  const int wv_m = wid >> 1;     // 0..1 -> 64-row band
  const int wv_n = wid & 1;      // 0..1 -> 64-col band
  const int fr = lane & 15;
  const int fg = lane >> 4;

  const unsigned short* aSrc[2]; int aDst[2];
  const unsigned short* bSrc[2]; int bDst[2];
  #pragma unroll
  for (int l = 0; l < 2; l++){
    const int s = l * 256 + tid;
    const int r = s >> 2, c = s & 3;
    const int co = (c ^ ((r >> 1) & 3)) << 3;
    aSrc[l] = A  + (size_t)(m0 + r) * K + co;
    bSrc[l] = BT + (size_t)(n0 + r) * K + co;
    aDst[l] = s * 16;
    bDst[l] = 8192 + s * 16;
  }

  int aOff[4], bOff[4];
  #pragma unroll
  for (int mi = 0; mi < 4; mi++){
    const int row = wv_m * 64 + mi * 16 + fr;
    aOff[mi] = row * 64 + ((fg ^ ((row >> 1) & 3)) << 4);
  }
  #pragma unroll
  for (int nj = 0; nj < 4; nj++){
    const int row = wv_n * 64 + nj * 16 + fr;
    bOff[nj] = 8192 + row * 64 + ((fg ^ ((row >> 1) & 3)) << 4);
  }

  f32x4 acc[4][4];
  #pragma unroll
  for (int i = 0; i < 4; i++)
    #pragma unroll
    for (int j = 0; j < 4; j++) acc[i][j] = (f32x4){0.f, 0.f, 0.f, 0.f};

#define STAGE7(sl, slot) do { \
    gload_lds16(aSrc[0] + (size_t)(sl) * 32, lds + (slot) + aDst[0]); \
    gload_lds16(aSrc[1] + (size_t)(sl) * 32, lds + (slot) + aDst[1]); \
    gload_lds16(bSrc[0] + (size_t)(sl) * 32, lds + (slot) + bDst[0]); \
    gload_lds16(bSrc[1] + (size_t)(sl) * 32, lds + (slot) + bDst[1]); \
  } while (0)

  const int NS = K >> 5;

  STAGE7(0, 0);
  STAGE7(1, SLOT);
  asm volatile("s_waitcnt vmcnt(4)" ::: "memory");
  __builtin_amdgcn_s_barrier();
  asm volatile("" ::: "memory");

  int cs = 0, cg = 2 * SLOT;
  for (int s = 0; s < NS; s++){
    short8 aF[4], bF[4];
    #pragma unroll
    for (int mi = 0; mi < 4; mi++)
      aF[mi] = *(const short8*)(lds + cs + aOff[mi]);
    #pragma unroll
    for (int nj = 0; nj < 4; nj++)
      bF[nj] = *(const short8*)(lds + cs + bOff[nj]);
    if (s + 2 < NS) STAGE7(s + 2, cg);
    #pragma unroll
    for (int mi = 0; mi < 4; mi++)
      #pragma unroll
      for (int nj = 0; nj < 4; nj++)
        acc[mi][nj] = mfma_bf16(aF[mi], bF[nj], acc[mi][nj]);

    if (s + 2 < NS){
      asm volatile("s_waitcnt vmcnt(4)" ::: "memory");
    } else if (s + 1 < NS){
      asm volatile("s_waitcnt vmcnt(0)" ::: "memory");
    }
    __builtin_amdgcn_s_barrier();
    asm volatile("" ::: "memory");

    cs += SLOT; if (cs == 3 * SLOT) cs = 0;
    cg += SLOT; if (cg == 3 * SLOT) cg = 0;
  }
#undef STAGE7

  #pragma unroll
  for (int mi = 0; mi < 4; mi++){
    const int mrow = m0 + wv_m * 64 + mi * 16 + fg * 4;
    #pragma unroll
    for (int nj = 0; nj < 4; nj++){
      const int ncol = n0 + wv_n * 64 + nj * 16 + fr;
      const float bv = bias[ncol];
      #pragma unroll
      for (int r2 = 0; r2 < 4; r2++){
        const size_t idx = (size_t)(mrow + r2) * N + ncol;
        epi_store<EPI>(outp, res, idx, acc[mi][nj][r2] + bv);
      }
    }
  }
}

// ===== causal flash attention =====
template<bool MASK>
__device__ __forceinline__ void attn_tile(
    const unsigned short* __restrict__ Kc, const unsigned short* __restrict__ Vc,
    const short8 (&qf)[4], int kvbase, int qg, int l31, int hi,
    float& m_r, float& lsum, f32x16& Oa, f32x16& Ob)
{
  f32x16 Sa = zero16();
  f32x16 Sb = zero16();
  const int xb = l31 & 7;
  #pragma unroll
  for (int kk = 0; kk < 4; kk++){
    const int x = kk * 2 + hi;
    const short8 k0 = *(const short8*)((const char*)Kc + l31 * 128 + ((x ^ xb) << 4));
    const short8 k1 = *(const short8*)((const char*)Kc + (l31 + 32) * 128 + ((x ^ xb) << 4));
    Sa = mfma32(k0, qf[kk], Sa);
    Sb = mfma32(k1, qf[kk], Sb);
  }
  if (MASK){
    #pragma unroll
    for (int r = 0; r < 16; r++){
      const int kva = kvbase + (r & 3) + 8 * (r >> 2) + 4 * hi;
      Sa[r] = (kva > qg)      ? -1e30f : Sa[r];
      Sb[r] = (kva + 32 > qg) ? -1e30f : Sb[r];
    }
  }
  float tmax = Sa[0];
  #pragma unroll
  for (int r = 1; r < 16; r++) tmax = fmaxf(tmax, Sa[r]);
  #pragma unroll
  for (int r = 0; r < 16; r++) tmax = fmaxf(tmax, Sb[r]);
  tmax = fmaxf(tmax, __shfl_xor(tmax, 32));
  if (__any(tmax > m_r + 10.0f)){
    const float mn = fmaxf(m_r, tmax);
    const float sc = exp2g(m_r - mn);
    m_r = mn;
    lsum *= sc;
    #pragma unroll
    for (int r = 0; r < 16; r++){ Oa[r] *= sc; Ob[r] *= sc; }
  }
  float rs = 0.0f;
  #pragma unroll
  for (int r = 0; r < 16; r++){
    Sa[r] = exp2g(Sa[r] - m_r); rs += Sa[r];
    Sb[r] = exp2g(Sb[r] - m_r); rs += Sb[r];
  }
  rs += __shfl_xor(rs, 32);
  lsum += rs;

  short8 pf[4];
  {
    uint32 a0 = cvtpk_bf(Sa[0], Sa[1]),   b0 = cvtpk_bf(Sa[4], Sa[5]);
    uint32 a1 = cvtpk_bf(Sa[2], Sa[3]),   b1 = cvtpk_bf(Sa[6], Sa[7]);
    plswap(a0, b0); plswap(a1, b1);
    uint32 a2 = cvtpk_bf(Sa[8], Sa[9]),   b2 = cvtpk_bf(Sa[12], Sa[13]);
    uint32 a3 = cvtpk_bf(Sa[10], Sa[11]), b3 = cvtpk_bf(Sa[14], Sa[15]);
    plswap(a2, b2); plswap(a3, b3);
    union { uint32 u[4]; short8 s; } m0, m1;
    m0.u[0] = a0; m0.u[1] = a1; m0.u[2] = b0; m0.u[3] = b1;
    m1.u[0] = a2; m1.u[1] = a3; m1.u[2] = b2; m1.u[3] = b3;
    pf[0] = m0.s; pf[1] = m1.s;
  }
  {
    uint32 a0 = cvtpk_bf(Sb[0], Sb[1]),   b0 = cvtpk_bf(Sb[4], Sb[5]);
    uint32 a1 = cvtpk_bf(Sb[2], Sb[3]),   b1 = cvtpk_bf(Sb[6], Sb[7]);
    plswap(a0, b0); plswap(a1, b1);
    uint32 a2 = cvtpk_bf(Sb[8], Sb[9]),   b2 = cvtpk_bf(Sb[12], Sb[13]);
    uint32 a3 = cvtpk_bf(Sb[10], Sb[11]), b3 = cvtpk_bf(Sb[14], Sb[15]);
    plswap(a2, b2); plswap(a3, b3);
    union { uint32 u[4]; short8 s; } m0, m1;
    m0.u[0] = a0; m0.u[1] = a1; m0.u[2] = b0; m0.u[3] = b1;
    m1.u[0] = a2; m1.u[1] = a3; m1.u[2] = b2; m1.u[3] = b3;
    pf[2] = m0.s; pf[3] = m1.s;
  }
  #pragma unroll
  for (int kk = 0; kk < 4; kk++){
    const int x = kk * 2 + hi;
    const short8 v0 = *(const short8*)((const char*)Vc + l31 * 128 + ((x ^ xb) << 4));
    const short8 v1 = *(const short8*)((const char*)Vc + (l31 + 32) * 128 + ((x ^ xb) << 4));
    Oa = mfma32(v0, pf[kk], Oa);
    Ob = mfma32(v1, pf[kk], Ob);
  }
}

__global__ __launch_bounds__(256) void attn_kernel(
    const unsigned short* __restrict__ qkv,
    const unsigned short* __restrict__ vt,
    unsigned short* __restrict__ y)
{
  __shared__ __align__(16) unsigned short Klds[2][4096];
  __shared__ __align__(16) unsigned short Vlds[2][4096];
  const int bid = blockIdx.x;
  const int bh = bid & 63;
  const int qb_i = 15 - (bid >> 6);   // heavy q-tiles first (LPT)
  const int b = bh >> 4, h = bh & 15;
  const int qb0 = qb_i * 128;
  const int tid = threadIdx.x;
  const int w = tid >> 6;
  const int lane = tid & 63;
  const int l31 = lane & 31;
  const int hi = lane >> 5;

  const int qrow_g = b * 2048 + qb0 + w * 32 + l31;
  const unsigned short* qp = qkv + (size_t)qrow_g * 3072 + h * 64;
  short8 qf[4];
  #pragma unroll
  for (int kk = 0; kk < 4; kk++){
    short8 raw = *(const short8*)&qp[kk * 16 + hi * 8];
    #pragma unroll
    for (int j = 0; j < 8; j++)
      qf[kk][j] = (short)f2bf(bf2f((unsigned short)raw[j]) * 0.18033688011112042f);
  }

  const int sr = tid >> 3;
  const int ce = ((tid & 7) ^ (sr & 7)) * 8;
  const unsigned short* kb = qkv + (size_t)(b * 2048) * 3072 + 1024 + h * 64;
  const unsigned short* vb = vt + (size_t)bh * 64 * 2048;

  f32x16 Oa = zero16(), Ob = zero16();
  float m_r = -1e30f, lsum = 0.0f;
  const int qmin = qb0 + w * 32;
  const int qmax = qmin + 31;
  const int qg = qmin + l31;
  const int nkv = (qb0 >> 6) + 2;

#define STAGE(t, bb) do { \
    const size_t kro = (size_t)((t) * 64 + sr) * 3072; \
    gload_lds16(kb + kro + ce,                         (char*)&Klds[bb][0] + tid * 16); \
    gload_lds16(kb + kro + (size_t)32 * 3072 + ce,     (char*)&Klds[bb][0] + 4096 + tid * 16); \
    gload_lds16(vb + (size_t)sr * 2048 + (t) * 64 + ce,        (char*)&Vlds[bb][0] + tid * 16); \
    gload_lds16(vb + (size_t)(sr + 32) * 2048 + (t) * 64 + ce, (char*)&Vlds[bb][0] + 4096 + tid * 16); \
  } while (0)

  STAGE(0, 0);
  __syncthreads();
  int cur = 0;
  for (int kvt = 0; kvt < nkv; kvt++){
    if (kvt + 1 < nkv){
      if (cur) STAGE(kvt + 1, 0); else STAGE(kvt + 1, 1);
    }
    if (kvt * 64 <= qmax){
      if (kvt * 64 + 63 <= qmin)
        attn_tile<false>(Klds[cur], Vlds[cur], qf, kvt * 64, qg, l31, hi, m_r, lsum, Oa, Ob);
      else
        attn_tile<true >(Klds[cur], Vlds[cur], qf, kvt * 64, qg, l31, hi, m_r, lsum, Oa, Ob);
    }
    __syncthreads();
    cur ^= 1;
  }
#undef STAGE

  const float inv = 1.0f / lsum;
  unsigned short* yp = y + (size_t)qrow_g * 1024 + h * 64;
  #pragma unroll
  for (int c2 = 0; c2 < 4; c2++){
    uint2v da, db;
    da.x = cvtpk_bf(Oa[4 * c2 + 0] * inv, Oa[4 * c2 + 1] * inv);
    da.y = cvtpk_bf(Oa[4 * c2 + 2] * inv, Oa[4 * c2 + 3] * inv);
    *(uint2v*)&yp[8 * c2 + 4 * hi] = da;
    db.x = cvtpk_bf(Ob[4 * c2 + 0] * inv, Ob[4 * c2 + 1] * inv);
    db.y = cvtpk_bf(Ob[4 * c2 + 2] * inv, Ob[4 * c2 + 3] * inv);
    *(uint2v*)&yp[32 + 8 * c2 + 4 * hi] = db;
  }
}

// ===== launch =====
extern "C" void kernel_launch(void* const* d_in, const int* in_sizes, int n_in,
                              void* d_out, int out_size, void* d_ws, size_t ws_size,
                              hipStream_t stream)
{
  const float* x      = (const float*)d_in[0];
  const float* ln1_w  = (const float*)d_in[1];
  const float* ln1_b  = (const float*)d_in[2];
  const float* w_attn = (const float*)d_in[3];
  const float* b_attn = (const float*)d_in[4];
  const float* w_proj = (const float*)d_in[5];
  const float* b_proj = (const float*)d_in[6];
  const float* ln2_w  = (const float*)d_in[7];
  const float* ln2_b  = (const float*)d_in[8];
  const float* w_fc   = (const float*)d_in[9];
  const float* b_fc   = (const float*)d_in[10];
  const float* w_fc2  = (const float*)d_in[11];
  const float* b_fc2  = (const float*)d_in[12];

  char* ws = (char*)d_ws;
  unsigned short* wbT_attn = (unsigned short*)(ws + 0);          //  [3072][1024]
  unsigned short* wbT_proj = (unsigned short*)(ws + 6291456);    //  [1024][1024]
  unsigned short* wbT_fc   = (unsigned short*)(ws + 8388608);    //  [4096][1024]
  unsigned short* wbT_fc2  = (unsigned short*)(ws + 16777216);   //  [1024][4096]
  unsigned short* h_bf     = (unsigned short*)(ws + 25165824);   //  [8192][1024]
  unsigned short* qkv_bf   = (unsigned short*)(ws + 41943040);   //  [8192][3072]
  unsigned short* vt_bf    = (unsigned short*)(ws + 92274688);   //  [64][64][2048]
  unsigned short* g_bf     = (unsigned short*)(ws + 41943040);   //  alias qkv+vt: [8192][4096]
  unsigned short* y_bf     = (unsigned short*)(ws + 109051904);  //  [8192][1024]
  unsigned short* x1_bf    = (unsigned short*)(ws + 125829120);  //  [8192][1024] bf16
  float* outf = (float*)d_out;

  // merged weight transpose (one launch, 12288 tiles)
  wtrans_all_kernel<<<12288, 256, 0, stream>>>(
      w_attn, wbT_attn, w_proj, wbT_proj, w_fc, wbT_fc, w_fc2, wbT_fc2);

  // LN1: x -> h_bf
  ln_kernel<<<8192, 256, 0, stream>>>(x, ln1_w, ln1_b, h_bf);
  // qkv = h @ w_attn + b_attn   (grid = 64 m x 12 n = 768, 2 blocks/CU)
  gemm5_kernel<EPI_BF16><<<768, 256, 0, stream>>>(
      h_bf, wbT_attn, b_attn, nullptr, qkv_bf, 8192, 3072, 1024);
  // V transpose for PV operand
  vtrans_kernel<<<dim3(64, 2, 64), 256, 0, stream>>>(qkv_bf, vt_bf);
  // causal flash attention -> y_bf  (heavy-first LPT ordering)
  attn_kernel<<<1024, 256, 0, stream>>>(qkv_bf, vt_bf, y_bf);
  // x1(bf16) = x + y @ w_proj + b_proj   (grid = 64 x 8 = 512, 3 blocks/CU)
  gemm7_kernel<EPI_RESF_OBF><<<512, 256, 0, stream>>>(
      y_bf, wbT_proj, b_proj, x, x1_bf, 8192, 1024, 1024);
  // LN2: x1(bf16) -> h_bf
  ln_bf16_kernel<<<8192, 256, 0, stream>>>(x1_bf, ln2_w, ln2_b, h_bf);
  // g = gelu(h2 @ w_fc + b_fc)   (grid = 64 x 16 = 1024, 2 blocks/CU)
  gemm5_kernel<EPI_GELU><<<1024, 256, 0, stream>>>(
      h_bf, wbT_fc, b_fc, nullptr, g_bf, 8192, 4096, 1024);
  // out(f32) = x1(bf16) + g @ w_fc2 + b_fc2   (grid = 512, 3 blocks/CU)
  gemm7_kernel<EPI_RESBF_OF32><<<512, 256, 0, stream>>>(
      g_bf, wbT_fc2, b_fc2, x1_bf, outf, 8192, 1024, 4096);
}